// Round 7
// baseline (416.729 us; speedup 1.0000x reference)
//
#include <hip/hip_runtime.h>
#include <math.h>

#define NODES 8192
#define NEDGE 262144
#define DIM 256

typedef float f32x16 __attribute__((ext_vector_type(16)));
typedef __bf16 bf16x8 __attribute__((ext_vector_type(8)));
typedef unsigned short u16;
typedef u16 u16x8 __attribute__((ext_vector_type(8)));

__device__ __forceinline__ float fast_tanh(float x) {
    float t = __expf(2.f * x);
    return 1.f - 2.f * __builtin_amdgcn_rcpf(t + 1.f);
}

// ---------------- CSR build (dst-indexed) ----------------
__global__ void k_zero(int* __restrict__ deg) {
    int i = blockIdx.x * blockDim.x + threadIdx.x;
    if (i < NODES) deg[i] = 0;
}

__global__ void k_deg(const int* __restrict__ dst, int* __restrict__ deg) {
    int e = blockIdx.x * blockDim.x + threadIdx.x;
    if (e < NEDGE) atomicAdd(&deg[dst[e]], 1);
}

__global__ void k_scan(const int* __restrict__ deg, int* __restrict__ rowptr,
                       int* __restrict__ cursor) {
    __shared__ int part[256];
    int t = threadIdx.x;
    int base = t * 32;
    int local[32];
    int s = 0;
    for (int i = 0; i < 32; ++i) { local[i] = s; s += deg[base + i]; }
    part[t] = s;
    __syncthreads();
    for (int off = 1; off < 256; off <<= 1) {
        int v = (t >= off) ? part[t - off] : 0;
        __syncthreads();
        part[t] += v;
        __syncthreads();
    }
    int excl = (t == 0) ? 0 : part[t - 1];
    for (int i = 0; i < 32; ++i) {
        int v = excl + local[i];
        rowptr[base + i] = v;
        cursor[base + i] = v;
    }
    if (t == 255) rowptr[NODES] = part[255];
}

__global__ void k_fill(const int* __restrict__ dst, int* __restrict__ cursor,
                       int* __restrict__ elist) {
    int e = blockIdx.x * blockDim.x + threadIdx.x;
    if (e < NEDGE) {
        int pos = atomicAdd(&cursor[dst[e]], 1);
        elist[pos] = e;
    }
}

// ---------------- W -> per-(gks,wave) contiguous fragment order ----------------
// wf[((gks*4 + w)*6 + mt*3 + pl)*512 + lane*8 + j]
//   = Wpl[w*64 + mt*32 + (lane&31)][gks*16 + (lane>>5)*8 + j]
__global__ void k_wfrag(const float* __restrict__ W, u16* __restrict__ wf) {
    int t = blockIdx.x * blockDim.x + threadIdx.x;
    if (t >= 16 * 4 * 2 * 64) return;
    int lane = t & 63;
    int mt = (t >> 6) & 1;
    int w = (t >> 7) & 3;
    int gks = t >> 9;
    int row = w * 64 + mt * 32 + (lane & 31);
    int k0 = gks * 16 + (lane >> 5) * 8;
    const float* p = W + (size_t)row * DIM + k0;
    u16x8 v1, v2, v3;
#pragma unroll
    for (int j = 0; j < 8; ++j) {
        float f = p[j];
        unsigned uf = __float_as_uint(f);
        float r = f - __uint_as_float(uf & 0xFFFF0000u);
        unsigned ur = __float_as_uint(r);
        float r2 = r - __uint_as_float(ur & 0xFFFF0000u);
        unsigned ur2 = __float_as_uint(r2);
        v1[j] = (u16)(uf >> 16);
        v2[j] = (u16)(ur >> 16);
        v3[j] = (u16)(ur2 >> 16);
    }
    size_t base = ((size_t)(gks * 4 + w) * 6 + mt * 3) * 512 + lane * 8;
    *(u16x8*)(wf + base)        = v1;
    *(u16x8*)(wf + base + 512)  = v2;
    *(u16x8*)(wf + base + 1024) = v3;
}

// ---------------- alpha via 3-split bf16 MFMA 32x32x16, v7 ----------------
// Same math as v6; K-chunk shrunk to 32 so LDS = 25.6 KB -> 6 blocks/CU.
// Inter-block phase skew keeps the MFMA pipe fed through staging phases.
__global__ __launch_bounds__(256, 4) void k_alpha_v7(
    const float* __restrict__ x, const int* __restrict__ src, const int* __restrict__ dst,
    const u16* __restrict__ wf,
    const float* __restrict__ bias, const float* __restrict__ amap,
    float* __restrict__ alpha)
{
    __shared__ u16 p_lds[2][3][4][64][8];   // [buf][plane][kb(8k)][edge][8] = 24 KB
    __shared__ float red[4][64];
    const int tid = threadIdx.x;
    const int w = tid >> 6;
    const int lane = tid & 63;
    const int l31 = lane & 31;
    const int g2 = lane >> 5;
    const int e0 = blockIdx.x * 64;

    // staging role: edge = tid&63, 8-k slice within 32-k chunk = tid>>6
    const int se = tid & 63;
    const int kq = tid >> 6;
    const int es = src[e0 + se];
    const int ed = dst[e0 + se];
    const float* xs = x + (size_t)es * DIM + kq * 8;
    const float* xd = x + (size_t)ed * DIM + kq * 8;

    f32x16 acc[2][2];
#pragma unroll
    for (int mt = 0; mt < 2; ++mt)
#pragma unroll
        for (int nt = 0; nt < 2; ++nt) acc[mt][nt] = (f32x16)0.f;

    const int PA[6] = {0, 0, 1, 0, 1, 2};
    const int PB[6] = {0, 1, 0, 2, 1, 0};

    bf16x8 afA[2][3], afB[2][3];
    float4 sv0, sv1, dv0, dv1;

#define STAGE_LOAD(C) { \
    sv0 = *(const float4*)(xs + (C) * 32); \
    sv1 = *(const float4*)(xs + (C) * 32 + 4); \
    dv0 = *(const float4*)(xd + (C) * 32); \
    dv1 = *(const float4*)(xd + (C) * 32 + 4); }

#define STAGE_WRITE(C) { \
    float pv[8] = {sv0.x * dv0.x, sv0.y * dv0.y, sv0.z * dv0.z, sv0.w * dv0.w, \
                   sv1.x * dv1.x, sv1.y * dv1.y, sv1.z * dv1.z, sv1.w * dv1.w}; \
    u16x8 v1, v2, v3; \
    _Pragma("unroll") for (int i = 0; i < 8; ++i) { \
        float f = pv[i]; \
        unsigned uf = __float_as_uint(f); \
        float r = f - __uint_as_float(uf & 0xFFFF0000u); \
        unsigned ur = __float_as_uint(r); \
        float r2 = r - __uint_as_float(ur & 0xFFFF0000u); \
        unsigned ur2 = __float_as_uint(r2); \
        v1[i] = (u16)(uf >> 16); \
        v2[i] = (u16)(ur >> 16); \
        v3[i] = (u16)(ur2 >> 16); } \
    *(u16x8*)&p_lds[(C) & 1][0][kq][se][0] = v1; \
    *(u16x8*)&p_lds[(C) & 1][1][kq][se][0] = v2; \
    *(u16x8*)&p_lds[(C) & 1][2][kq][se][0] = v3; }

#define PREFA(DST, GKS) { \
    const u16* pb = wf + ((size_t)((GKS) * 4 + w) * 6) * 512 + lane * 8; \
    _Pragma("unroll") for (int mt = 0; mt < 2; ++mt) \
    _Pragma("unroll") for (int pl = 0; pl < 3; ++pl) \
        DST[mt][pl] = *(const bf16x8*)(const void*)(pb + (mt * 3 + pl) * 512); }

#define KSTEP(C, KS) { \
    const int gks_ = (C) * 2 + (KS); \
    if (gks_ + 1 < 16) { \
        if (gks_ & 1) { PREFA(afA, gks_ + 1) } else { PREFA(afB, gks_ + 1) } \
    } \
    bf16x8 bfr[2][3]; \
    _Pragma("unroll") for (int nt = 0; nt < 2; ++nt) \
    _Pragma("unroll") for (int pl = 0; pl < 3; ++pl) \
        bfr[nt][pl] = *(const bf16x8*)(const void*)&p_lds[(C) & 1][pl][2 * (KS) + g2][nt * 32 + l31][0]; \
    _Pragma("unroll") for (int pr = 0; pr < 6; ++pr) \
    _Pragma("unroll") for (int mt = 0; mt < 2; ++mt) \
    _Pragma("unroll") for (int nt = 0; nt < 2; ++nt) \
        acc[mt][nt] = __builtin_amdgcn_mfma_f32_32x32x16_bf16( \
            (gks_ & 1) ? afB[mt][PA[pr]] : afA[mt][PA[pr]], \
            bfr[nt][PB[pr]], acc[mt][nt], 0, 0, 0); }

    // prologue: stage chunk 0, preload A step 0
    STAGE_LOAD(0)
    PREFA(afA, 0)
    STAGE_WRITE(0)
    __syncthreads();

#pragma unroll
    for (int c = 0; c < 8; ++c) {
        if (c < 7) STAGE_LOAD(c + 1)
        KSTEP(c, 0)
        if (c < 7) STAGE_WRITE(c + 1)
        KSTEP(c, 1)
        __syncthreads();
    }
#undef STAGE_LOAD
#undef STAGE_WRITE
#undef PREFA
#undef KSTEP

    // ---- epilogue: alpha[e] = sum_out amap*tanh(h+bias) ----
    float part[2] = {0.f, 0.f};
#pragma unroll
    for (int mt = 0; mt < 2; ++mt)
#pragma unroll
        for (int r = 0; r < 16; ++r) {
            int o = 64 * w + 32 * mt + (r & 3) + 8 * (r >> 2) + 4 * g2;
            float bo = bias[o], ao = amap[o];
#pragma unroll
            for (int nt = 0; nt < 2; ++nt)
                part[nt] += ao * fast_tanh(acc[mt][nt][r] + bo);
        }
#pragma unroll
    for (int nt = 0; nt < 2; ++nt) {
        float p = part[nt];
        p += __shfl_xor(p, 32);
        if (lane < 32) red[w][nt * 32 + lane] = p;
    }
    __syncthreads();
    if (tid < 64) alpha[e0 + tid] = red[0][tid] + red[1][tid] + red[2][tid] + red[3][tid];
}

// ---------------- per-node segment softmax + weighted aggregate ----------------
__global__ void k_aggregate(
    const float* __restrict__ x, const int* __restrict__ src,
    const float* __restrict__ alpha, const int* __restrict__ rowptr,
    const int* __restrict__ elist, float* __restrict__ agg)
{
    int gw = (blockIdx.x * blockDim.x + threadIdx.x) >> 6;
    int lane = threadIdx.x & 63;
    if (gw >= NODES) return;
    int start = rowptr[gw], end = rowptr[gw + 1];
    int deg = end - start;
    float m = -INFINITY;
    for (int i = lane; i < deg; i += 64) m = fmaxf(m, alpha[elist[start + i]]);
#pragma unroll
    for (int off = 32; off > 0; off >>= 1) m = fmaxf(m, __shfl_xor(m, off));
    float ssum = 0.f;
    for (int i = lane; i < deg; i += 64) ssum += expf(alpha[elist[start + i]] - m);
#pragma unroll
    for (int off = 32; off > 0; off >>= 1) ssum += __shfl_xor(ssum, off);
    float a0 = 0.f, a1 = 0.f, a2 = 0.f, a3 = 0.f;
    for (int i = 0; i < deg; ++i) {
        int e = elist[start + i];
        float w = expf(alpha[e] - m);
        const float4 v = *(const float4*)(x + (size_t)src[e] * DIM + lane * 4);
        a0 += w * v.x; a1 += w * v.y; a2 += w * v.z; a3 += w * v.w;
    }
    float inv = 1.f / (ssum + 1e-16f);
    float4 r; r.x = a0 * inv; r.y = a1 * inv; r.z = a2 * inv; r.w = a3 * inv;
    *(float4*)(agg + (size_t)gw * DIM + lane * 4) = r;
}

// ---------------- out = agg@pwa^T + x@pwo^T + biases ----------------
__global__ __launch_bounds__(256, 2) void k_out(
    const float* __restrict__ agg, const float* __restrict__ x,
    const float* __restrict__ Wa, const float* __restrict__ Wo,
    const float* __restrict__ ba, const float* __restrict__ bo,
    float* __restrict__ outb)
{
    __shared__ float As[256][36];
    __shared__ float Bs[64][36];
    __shared__ float Cs[64][68];
    const int tid = threadIdx.x;
    const int oo = tid >> 3, ee = tid & 7;
    const int n0 = blockIdx.x * 64;
    const int bn = tid >> 2, bks = tid & 3;

    float acc[8][8];
#pragma unroll
    for (int j = 0; j < 8; ++j)
#pragma unroll
        for (int je = 0; je < 8; ++je) acc[j][je] = 0.f;

    for (int cc = 0; cc < 16; ++cc) {
        const float* Wsrc = (cc < 8) ? Wa : Wo;
        const float* Bsrc = (cc < 8) ? agg : x;
        const int kc = (cc & 7) * 32;
        {
            const float4* g = (const float4*)(Wsrc + (size_t)tid * DIM + kc);
            float4* l = (float4*)(&As[tid][0]);
#pragma unroll
            for (int i = 0; i < 8; ++i) l[i] = g[i];
        }
        {
            const float4* g = (const float4*)(Bsrc + (size_t)(n0 + bn) * DIM + kc + bks * 8);
            *(float4*)(&Bs[bn][bks * 8])     = g[0];
            *(float4*)(&Bs[bn][bks * 8 + 4]) = g[1];
        }
        __syncthreads();
#pragma unroll
        for (int kq = 0; kq < 8; ++kq) {
            float4 av[8], bv[8];
#pragma unroll
            for (int j = 0; j < 8; ++j)  av[j] = *(const float4*)(&As[oo + 32 * j][kq * 4]);
#pragma unroll
            for (int je = 0; je < 8; ++je) bv[je] = *(const float4*)(&Bs[ee + 8 * je][kq * 4]);
#pragma unroll
            for (int j = 0; j < 8; ++j)
#pragma unroll
                for (int je = 0; je < 8; ++je) {
                    acc[j][je] += av[j].x * bv[je].x;
                    acc[j][je] += av[j].y * bv[je].y;
                    acc[j][je] += av[j].z * bv[je].z;
                    acc[j][je] += av[j].w * bv[je].w;
                }
        }
        __syncthreads();
    }

    float bsum[8];
#pragma unroll
    for (int j = 0; j < 8; ++j) bsum[j] = ba[oo + 32 * j] + bo[oo + 32 * j];

    for (int c = 0; c < 4; ++c) {
#pragma unroll
        for (int jh = 0; jh < 2; ++jh) {
            int j = 2 * c + jh;
#pragma unroll
            for (int je = 0; je < 8; ++je)
                Cs[ee + 8 * je][oo + 32 * jh] = acc[j][je] + bsum[j];
        }
        __syncthreads();
        int ol = tid & 63, wv = tid >> 6;
        for (int r = wv; r < 64; r += 4)
            outb[(size_t)(n0 + r) * DIM + c * 64 + ol] = Cs[r][ol];
        __syncthreads();
    }
}

// ---------------- BN column stats (fp64 partials) ----------------
__global__ void k_colstat(const float* __restrict__ outb, double* __restrict__ psum,
                          double* __restrict__ psq) {
    int g = blockIdx.x, t = threadIdx.x;
    double s = 0.0, q = 0.0;
    const float* p = outb + (size_t)g * 256 * DIM + t;
    for (int r = 0; r < 256; ++r) { double v = (double)p[(size_t)r * DIM]; s += v; q += v * v; }
    psum[g * DIM + t] = s;
    psq[g * DIM + t] = q;
}

__global__ void k_bnparam(const double* __restrict__ psum, const double* __restrict__ psq,
                          const float* __restrict__ gamma, const float* __restrict__ beta,
                          float* __restrict__ scale, float* __restrict__ shift) {
    int t = threadIdx.x;
    double s = 0.0, q = 0.0;
    for (int g = 0; g < 32; ++g) { s += psum[g * DIM + t]; q += psq[g * DIM + t]; }
    double mean = s / (double)NODES;
    double var = q / (double)NODES - mean * mean;
    float sc = (float)((double)gamma[t] / sqrt(var + 1e-5));
    scale[t] = sc;
    shift[t] = (float)((double)beta[t] - mean * (double)sc);
}

// ---------------- affine + SELU + pooling score ----------------
__global__ void k_bnselu(float* __restrict__ outb, const float* __restrict__ scale,
                         const float* __restrict__ shift, const float* __restrict__ yw,
                         const float* __restrict__ yb, float* __restrict__ y) {
    int gw = (blockIdx.x * blockDim.x + threadIdx.x) >> 6;
    int lane = threadIdx.x & 63;
    if (gw >= NODES) return;
    float4 v  = *(const float4*)(outb + (size_t)gw * DIM + lane * 4);
    float4 sc = *(const float4*)(scale + lane * 4);
    float4 sh = *(const float4*)(shift + lane * 4);
    const float SL = 1.0507009873554805f, SA = 1.6732632423543772f;
    float4 o;
    o.x = v.x * sc.x + sh.x;
    o.y = v.y * sc.y + sh.y;
    o.z = v.z * sc.z + sh.z;
    o.w = v.w * sc.w + sh.w;
    o.x = (o.x > 0.f) ? SL * o.x : SL * SA * expm1f(o.x);
    o.y = (o.y > 0.f) ? SL * o.y : SL * SA * expm1f(o.y);
    o.z = (o.z > 0.f) ? SL * o.z : SL * SA * expm1f(o.z);
    o.w = (o.w > 0.f) ? SL * o.w : SL * SA * expm1f(o.w);
    *(float4*)(outb + (size_t)gw * DIM + lane * 4) = o;
    float4 w = *(const float4*)(yw + lane * 4);
    float z = o.x * w.x + o.y * w.y + o.z * w.z + o.w * w.w;
#pragma unroll
    for (int off = 32; off > 0; off >>= 1) z += __shfl_xor(z, off);
    if (lane == 0) y[gw] = 1.f / (1.f + expf(-(z + yb[0])));
}

// ---------------- per-batch bitonic top-k (val desc, idx asc — jax semantics) ----------------
__global__ void k_topk(const float* __restrict__ y, float* __restrict__ svals,
                       int* __restrict__ sidx) {
    __shared__ float v[1024];
    __shared__ int  id[1024];
    int b = blockIdx.x, t = threadIdx.x;   // 512 threads
    v[t] = y[b * 1024 + t];           id[t] = t;
    v[t + 512] = y[b * 1024 + t + 512]; id[t + 512] = t + 512;
    __syncthreads();
    for (int k = 2; k <= 1024; k <<= 1) {
        for (int j = k >> 1; j > 0; j >>= 1) {
            for (int i = t; i < 1024; i += 512) {
                int l = i ^ j;
                if (l > i) {
                    float vi = v[i], vl = v[l];
                    int ii = id[i], il = id[l];
                    bool precede = (vi > vl) || (vi == vl && ii < il);
                    bool dirDesc = ((i & k) == 0);
                    bool sw = dirDesc ? !precede : precede;
                    if (sw) { v[i] = vl; v[l] = vi; id[i] = il; id[l] = ii; }
                }
            }
            __syncthreads();
        }
    }
    if (t < 512) { svals[b * 512 + t] = v[t]; sidx[b * 512 + t] = id[t]; }
}

// ---------------- gather + gate ----------------
__global__ void k_gather(const float* __restrict__ outb, const float* __restrict__ svals,
                         const int* __restrict__ sidx, float* __restrict__ dout) {
    int gw = (blockIdx.x * blockDim.x + threadIdx.x) >> 6;
    int lane = threadIdx.x & 63;
    int b = gw >> 9, r = gw & 511;
    float val = svals[b * 512 + r];
    int idn = sidx[b * 512 + r];
    float4 vv = *(const float4*)(outb + (size_t)(b * 1024 + idn) * DIM + lane * 4);
    vv.x *= val; vv.y *= val; vv.z *= val; vv.w *= val;
    *(float4*)(dout + (size_t)(b * 512 + r) * DIM + lane * 4) = vv;
}

extern "C" void kernel_launch(void* const* d_in, const int* in_sizes, int n_in,
                              void* d_out, int out_size, void* d_ws, size_t ws_size,
                              hipStream_t stream) {
    const float* x     = (const float*)d_in[0];
    const int* edges   = (const int*)d_in[1];
    const float* att_w = (const float*)d_in[2];
    const float* att_b = (const float*)d_in[3];
    const float* amap  = (const float*)d_in[4];
    const float* pwa_w = (const float*)d_in[5];
    const float* pwa_b = (const float*)d_in[6];
    const float* pwo_w = (const float*)d_in[7];
    const float* pwo_b = (const float*)d_in[8];
    const float* gamma = (const float*)d_in[9];
    const float* beta  = (const float*)d_in[10];
    const float* yw    = (const float*)d_in[11];
    const float* yb    = (const float*)d_in[12];
    float* out = (float*)d_out;
    const int* src = edges;
    const int* dst = edges + NEDGE;

    char* ws = (char*)d_ws;
    size_t off = 0;
    auto alloc = [&](size_t b) { void* p = ws + off; off = (off + b + 255) & ~(size_t)255; return p; };
    float* alpha  = (float*)alloc((size_t)NEDGE * 4);
    int*   elist  = (int*)alloc((size_t)NEDGE * 4);
    float* agg    = (float*)alloc((size_t)NODES * DIM * 4);
    float* outb   = (float*)alloc((size_t)NODES * DIM * 4);
    int*   deg    = (int*)alloc(NODES * 4);
    int*   rowptr = (int*)alloc((NODES + 1) * 4);
    int*   cursor = (int*)alloc(NODES * 4);
    double* psum  = (double*)alloc(32 * DIM * 8);
    double* psq   = (double*)alloc(32 * DIM * 8);
    float* scale  = (float*)alloc(DIM * 4);
    float* shift  = (float*)alloc(DIM * 4);
    float* yv     = (float*)alloc(NODES * 4);
    float* svals  = (float*)alloc(8 * 512 * 4);
    int*   sidx   = (int*)alloc(8 * 512 * 4);
    u16*   wf     = (u16*)alloc((size_t)16 * 4 * 6 * 512 * 2);

    k_wfrag<<<32, 256, 0, stream>>>(att_w, wf);
    k_zero<<<NODES / 256, 256, 0, stream>>>(deg);
    k_deg<<<NEDGE / 256, 256, 0, stream>>>(dst, deg);
    k_scan<<<1, 256, 0, stream>>>(deg, rowptr, cursor);
    k_fill<<<NEDGE / 256, 256, 0, stream>>>(dst, cursor, elist);
    k_alpha_v7<<<NEDGE / 64, 256, 0, stream>>>(x, src, dst, wf, att_b, amap, alpha);
    k_aggregate<<<NODES / 4, 256, 0, stream>>>(x, src, alpha, rowptr, elist, agg);
    k_out<<<NODES / 64, 256, 0, stream>>>(agg, x, pwa_w, pwo_w, pwa_b, pwo_b, outb);
    k_colstat<<<32, 256, 0, stream>>>(outb, psum, psq);
    k_bnparam<<<1, 256, 0, stream>>>(psum, psq, gamma, beta, scale, shift);
    k_bnselu<<<NODES / 4, 256, 0, stream>>>(outb, scale, shift, yw, yb, yv);
    k_topk<<<8, 512, 0, stream>>>(yv, svals, sidx);
    k_gather<<<(8 * 512) / 4, 256, 0, stream>>>(outb, svals, sidx, out);
}

// Round 8
// 411.863 us; speedup vs baseline: 1.0118x; 1.0118x over previous
//
#include <hip/hip_runtime.h>
#include <math.h>

#define NODES 8192
#define NEDGE 262144
#define DIM 256

typedef float f32x16 __attribute__((ext_vector_type(16)));
typedef _Float16 f16x8 __attribute__((ext_vector_type(8)));
typedef unsigned short u16;
typedef u16 u16x8 __attribute__((ext_vector_type(8)));

__device__ __forceinline__ float fast_tanh(float x) {
    float t = __expf(2.f * x);
    return 1.f - 2.f * __builtin_amdgcn_rcpf(t + 1.f);
}

__device__ __forceinline__ u16 h_bits(_Float16 h) {
    u16 r; __builtin_memcpy(&r, &h, 2); return r;
}

// ---------------- CSR build (dst-indexed) ----------------
__global__ void k_zero(int* __restrict__ deg) {
    int i = blockIdx.x * blockDim.x + threadIdx.x;
    if (i < NODES) deg[i] = 0;
}

__global__ void k_deg(const int* __restrict__ dst, int* __restrict__ deg) {
    int e = blockIdx.x * blockDim.x + threadIdx.x;
    if (e < NEDGE) atomicAdd(&deg[dst[e]], 1);
}

__global__ void k_scan(const int* __restrict__ deg, int* __restrict__ rowptr,
                       int* __restrict__ cursor) {
    __shared__ int part[256];
    int t = threadIdx.x;
    int base = t * 32;
    int local[32];
    int s = 0;
    for (int i = 0; i < 32; ++i) { local[i] = s; s += deg[base + i]; }
    part[t] = s;
    __syncthreads();
    for (int off = 1; off < 256; off <<= 1) {
        int v = (t >= off) ? part[t - off] : 0;
        __syncthreads();
        part[t] += v;
        __syncthreads();
    }
    int excl = (t == 0) ? 0 : part[t - 1];
    for (int i = 0; i < 32; ++i) {
        int v = excl + local[i];
        rowptr[base + i] = v;
        cursor[base + i] = v;
    }
    if (t == 255) rowptr[NODES] = part[255];
}

__global__ void k_fill(const int* __restrict__ dst, int* __restrict__ cursor,
                       int* __restrict__ elist) {
    int e = blockIdx.x * blockDim.x + threadIdx.x;
    if (e < NEDGE) {
        int pos = atomicAdd(&cursor[dst[e]], 1);
        elist[pos] = e;
    }
}

// ---------------- W -> fp16 2-plane fragment order (plane2 pre-scaled 2^11) --
// wf[((gks*4 + w)*4 + mt*2 + pl)*512 + lane*8 + j]
//   = Wpl[w*64 + mt*32 + (lane&31)][gks*16 + (lane>>5)*8 + j]
__global__ void k_wfrag(const float* __restrict__ W, u16* __restrict__ wf) {
    int t = blockIdx.x * blockDim.x + threadIdx.x;
    if (t >= 16 * 4 * 2 * 64) return;
    int lane = t & 63;
    int mt = (t >> 6) & 1;
    int w = (t >> 7) & 3;
    int gks = t >> 9;
    int row = w * 64 + mt * 32 + (lane & 31);
    int k0 = gks * 16 + (lane >> 5) * 8;
    const float* p = W + (size_t)row * DIM + k0;
    u16x8 v1, v2;
#pragma unroll
    for (int j = 0; j < 8; ++j) {
        float f = p[j];
        _Float16 h1 = (_Float16)f;
        float f1 = (float)h1;
        _Float16 h2 = (_Float16)((f - f1) * 2048.f);
        v1[j] = h_bits(h1);
        v2[j] = h_bits(h2);
    }
    size_t base = ((size_t)(gks * 4 + w) * 4 + mt * 2) * 512 + lane * 8;
    *(u16x8*)(wf + base)       = v1;
    *(u16x8*)(wf + base + 512) = v2;
}

// ---------------- alpha via fp16 2-split MFMA 32x32x16, v8 ----------------
// 3 products: a1b1 -> accM ; a1b2s + a2s b1 -> accC (planes-2 pre-scaled 2^11)
// h = accM + accC * 2^-11. Structure = v6 (best base): 64 edges/block,
// K-chunks of 64, dbuf LDS, A ping-pong, launch_bounds(256,2).
__global__ __launch_bounds__(256, 2) void k_alpha_v8(
    const float* __restrict__ x, const int* __restrict__ src, const int* __restrict__ dst,
    const u16* __restrict__ wf,
    const float* __restrict__ bias, const float* __restrict__ amap,
    float* __restrict__ alpha)
{
    __shared__ u16 p_lds[2][2][8][64][8];   // [buf][plane][kb(8k)][edge][8] = 32 KB
    __shared__ float red[4][64];
    const int tid = threadIdx.x;
    const int w = tid >> 6;
    const int lane = tid & 63;
    const int l31 = lane & 31;
    const int g2 = lane >> 5;
    const int e0 = blockIdx.x * 64;

    // staging role: edge = tid&63, 16-k slice within 64-chunk = tid>>6
    const int se = tid & 63;
    const int kq = tid >> 6;
    const int es = src[e0 + se];
    const int ed = dst[e0 + se];
    const float* xs = x + (size_t)es * DIM + kq * 16;
    const float* xd = x + (size_t)ed * DIM + kq * 16;

    f32x16 accM[2][2], accC[2][2];
#pragma unroll
    for (int mt = 0; mt < 2; ++mt)
#pragma unroll
        for (int nt = 0; nt < 2; ++nt) { accM[mt][nt] = (f32x16)0.f; accC[mt][nt] = (f32x16)0.f; }

    f16x8 afA[2][2], afB[2][2];
    float4 sv[4], dv[4];

#define STAGE_LOAD(C) { \
    _Pragma("unroll") for (int j = 0; j < 4; ++j) { \
        sv[j] = *(const float4*)(xs + (C) * 64 + j * 4); \
        dv[j] = *(const float4*)(xd + (C) * 64 + j * 4); } }

#define STAGE_WRITE(C) { \
    _Pragma("unroll") for (int q = 0; q < 2; ++q) { \
        u16x8 v1, v2; \
        _Pragma("unroll") for (int i = 0; i < 8; ++i) { \
            int idx = q * 8 + i; \
            float f = ((const float*)sv)[idx] * ((const float*)dv)[idx]; \
            _Float16 h1 = (_Float16)f; \
            float f1 = (float)h1; \
            _Float16 h2 = (_Float16)((f - f1) * 2048.f); \
            v1[i] = h_bits(h1); \
            v2[i] = h_bits(h2); } \
        const int kb = kq * 2 + q; \
        *(u16x8*)&p_lds[(C) & 1][0][kb][se][0] = v1; \
        *(u16x8*)&p_lds[(C) & 1][1][kb][se][0] = v2; } }

#define PREFA(DST, GKS) { \
    const u16* pb = wf + ((size_t)((GKS) * 4 + w) * 4) * 512 + lane * 8; \
    _Pragma("unroll") for (int mt = 0; mt < 2; ++mt) \
    _Pragma("unroll") for (int pl = 0; pl < 2; ++pl) \
        DST[mt][pl] = *(const f16x8*)(const void*)(pb + (mt * 2 + pl) * 512); }

#define KSTEP(C, KS) { \
    const int gks_ = (C) * 4 + (KS); \
    if (gks_ + 1 < 16) { \
        if (gks_ & 1) { PREFA(afA, gks_ + 1) } else { PREFA(afB, gks_ + 1) } \
    } \
    f16x8 bfr[2][2]; \
    _Pragma("unroll") for (int nt = 0; nt < 2; ++nt) \
    _Pragma("unroll") for (int pl = 0; pl < 2; ++pl) \
        bfr[nt][pl] = *(const f16x8*)(const void*)&p_lds[(C) & 1][pl][2 * (KS) + g2][nt * 32 + l31][0]; \
    _Pragma("unroll") for (int mt = 0; mt < 2; ++mt) \
    _Pragma("unroll") for (int nt = 0; nt < 2; ++nt) { \
        f16x8 a1 = (gks_ & 1) ? afB[mt][0] : afA[mt][0]; \
        f16x8 a2 = (gks_ & 1) ? afB[mt][1] : afA[mt][1]; \
        accM[mt][nt] = __builtin_amdgcn_mfma_f32_32x32x16_f16(a1, bfr[nt][0], accM[mt][nt], 0, 0, 0); \
        accC[mt][nt] = __builtin_amdgcn_mfma_f32_32x32x16_f16(a1, bfr[nt][1], accC[mt][nt], 0, 0, 0); \
        accC[mt][nt] = __builtin_amdgcn_mfma_f32_32x32x16_f16(a2, bfr[nt][0], accC[mt][nt], 0, 0, 0); } }

    // prologue: stage chunk 0, preload A step 0
    STAGE_LOAD(0)
    PREFA(afA, 0)
    STAGE_WRITE(0)
    __syncthreads();

#pragma unroll
    for (int c = 0; c < 4; ++c) {
        if (c < 3) STAGE_LOAD(c + 1)
        KSTEP(c, 0)
        KSTEP(c, 1)
        if (c < 3) STAGE_WRITE(c + 1)
        KSTEP(c, 2)
        KSTEP(c, 3)
        __syncthreads();
    }
#undef STAGE_LOAD
#undef STAGE_WRITE
#undef PREFA
#undef KSTEP

    // ---- epilogue: alpha[e] = sum_out amap*tanh(h+bias), h = M + C*2^-11 ----
    float part[2] = {0.f, 0.f};
#pragma unroll
    for (int mt = 0; mt < 2; ++mt)
#pragma unroll
        for (int r = 0; r < 16; ++r) {
            int o = 64 * w + 32 * mt + (r & 3) + 8 * (r >> 2) + 4 * g2;
            float bo = bias[o], ao = amap[o];
#pragma unroll
            for (int nt = 0; nt < 2; ++nt) {
                float h = accM[mt][nt][r] + accC[mt][nt][r] * 4.8828125e-4f;
                part[nt] += ao * fast_tanh(h + bo);
            }
        }
#pragma unroll
    for (int nt = 0; nt < 2; ++nt) {
        float p = part[nt];
        p += __shfl_xor(p, 32);
        if (lane < 32) red[w][nt * 32 + lane] = p;
    }
    __syncthreads();
    if (tid < 64) alpha[e0 + tid] = red[0][tid] + red[1][tid] + red[2][tid] + red[3][tid];
}

// ---------------- per-node segment softmax + weighted aggregate ----------------
__global__ void k_aggregate(
    const float* __restrict__ x, const int* __restrict__ src,
    const float* __restrict__ alpha, const int* __restrict__ rowptr,
    const int* __restrict__ elist, float* __restrict__ agg)
{
    int gw = (blockIdx.x * blockDim.x + threadIdx.x) >> 6;
    int lane = threadIdx.x & 63;
    if (gw >= NODES) return;
    int start = rowptr[gw], end = rowptr[gw + 1];
    int deg = end - start;
    float m = -INFINITY;
    for (int i = lane; i < deg; i += 64) m = fmaxf(m, alpha[elist[start + i]]);
#pragma unroll
    for (int off = 32; off > 0; off >>= 1) m = fmaxf(m, __shfl_xor(m, off));
    float ssum = 0.f;
    for (int i = lane; i < deg; i += 64) ssum += expf(alpha[elist[start + i]] - m);
#pragma unroll
    for (int off = 32; off > 0; off >>= 1) ssum += __shfl_xor(ssum, off);
    float a0 = 0.f, a1 = 0.f, a2 = 0.f, a3 = 0.f;
    for (int i = 0; i < deg; ++i) {
        int e = elist[start + i];
        float w = expf(alpha[e] - m);
        const float4 v = *(const float4*)(x + (size_t)src[e] * DIM + lane * 4);
        a0 += w * v.x; a1 += w * v.y; a2 += w * v.z; a3 += w * v.w;
    }
    float inv = 1.f / (ssum + 1e-16f);
    float4 r; r.x = a0 * inv; r.y = a1 * inv; r.z = a2 * inv; r.w = a3 * inv;
    *(float4*)(agg + (size_t)gw * DIM + lane * 4) = r;
}

// ---------------- out = agg@pwa^T + x@pwo^T + biases ----------------
__global__ __launch_bounds__(256, 2) void k_out(
    const float* __restrict__ agg, const float* __restrict__ x,
    const float* __restrict__ Wa, const float* __restrict__ Wo,
    const float* __restrict__ ba, const float* __restrict__ bo,
    float* __restrict__ outb)
{
    __shared__ float As[256][36];
    __shared__ float Bs[64][36];
    __shared__ float Cs[64][68];
    const int tid = threadIdx.x;
    const int oo = tid >> 3, ee = tid & 7;
    const int n0 = blockIdx.x * 64;
    const int bn = tid >> 2, bks = tid & 3;

    float acc[8][8];
#pragma unroll
    for (int j = 0; j < 8; ++j)
#pragma unroll
        for (int je = 0; je < 8; ++je) acc[j][je] = 0.f;

    for (int cc = 0; cc < 16; ++cc) {
        const float* Wsrc = (cc < 8) ? Wa : Wo;
        const float* Bsrc = (cc < 8) ? agg : x;
        const int kc = (cc & 7) * 32;
        {
            const float4* g = (const float4*)(Wsrc + (size_t)tid * DIM + kc);
            float4* l = (float4*)(&As[tid][0]);
#pragma unroll
            for (int i = 0; i < 8; ++i) l[i] = g[i];
        }
        {
            const float4* g = (const float4*)(Bsrc + (size_t)(n0 + bn) * DIM + kc + bks * 8);
            *(float4*)(&Bs[bn][bks * 8])     = g[0];
            *(float4*)(&Bs[bn][bks * 8 + 4]) = g[1];
        }
        __syncthreads();
#pragma unroll
        for (int kq = 0; kq < 8; ++kq) {
            float4 av[8], bv[8];
#pragma unroll
            for (int j = 0; j < 8; ++j)  av[j] = *(const float4*)(&As[oo + 32 * j][kq * 4]);
#pragma unroll
            for (int je = 0; je < 8; ++je) bv[je] = *(const float4*)(&Bs[ee + 8 * je][kq * 4]);
#pragma unroll
            for (int j = 0; j < 8; ++j)
#pragma unroll
                for (int je = 0; je < 8; ++je) {
                    acc[j][je] += av[j].x * bv[je].x;
                    acc[j][je] += av[j].y * bv[je].y;
                    acc[j][je] += av[j].z * bv[je].z;
                    acc[j][je] += av[j].w * bv[je].w;
                }
        }
        __syncthreads();
    }

    float bsum[8];
#pragma unroll
    for (int j = 0; j < 8; ++j) bsum[j] = ba[oo + 32 * j] + bo[oo + 32 * j];

    for (int c = 0; c < 4; ++c) {
#pragma unroll
        for (int jh = 0; jh < 2; ++jh) {
            int j = 2 * c + jh;
#pragma unroll
            for (int je = 0; je < 8; ++je)
                Cs[ee + 8 * je][oo + 32 * jh] = acc[j][je] + bsum[j];
        }
        __syncthreads();
        int ol = tid & 63, wv = tid >> 6;
        for (int r = wv; r < 64; r += 4)
            outb[(size_t)(n0 + r) * DIM + c * 64 + ol] = Cs[r][ol];
        __syncthreads();
    }
}

// ---------------- BN column stats (fp64 partials) ----------------
__global__ void k_colstat(const float* __restrict__ outb, double* __restrict__ psum,
                          double* __restrict__ psq) {
    int g = blockIdx.x, t = threadIdx.x;
    double s = 0.0, q = 0.0;
    const float* p = outb + (size_t)g * 256 * DIM + t;
    for (int r = 0; r < 256; ++r) { double v = (double)p[(size_t)r * DIM]; s += v; q += v * v; }
    psum[g * DIM + t] = s;
    psq[g * DIM + t] = q;
}

__global__ void k_bnparam(const double* __restrict__ psum, const double* __restrict__ psq,
                          const float* __restrict__ gamma, const float* __restrict__ beta,
                          float* __restrict__ scale, float* __restrict__ shift) {
    int t = threadIdx.x;
    double s = 0.0, q = 0.0;
    for (int g = 0; g < 32; ++g) { s += psum[g * DIM + t]; q += psq[g * DIM + t]; }
    double mean = s / (double)NODES;
    double var = q / (double)NODES - mean * mean;
    float sc = (float)((double)gamma[t] / sqrt(var + 1e-5));
    scale[t] = sc;
    shift[t] = (float)((double)beta[t] - mean * (double)sc);
}

// ---------------- affine + SELU + pooling score ----------------
__global__ void k_bnselu(float* __restrict__ outb, const float* __restrict__ scale,
                         const float* __restrict__ shift, const float* __restrict__ yw,
                         const float* __restrict__ yb, float* __restrict__ y) {
    int gw = (blockIdx.x * blockDim.x + threadIdx.x) >> 6;
    int lane = threadIdx.x & 63;
    if (gw >= NODES) return;
    float4 v  = *(const float4*)(outb + (size_t)gw * DIM + lane * 4);
    float4 sc = *(const float4*)(scale + lane * 4);
    float4 sh = *(const float4*)(shift + lane * 4);
    const float SL = 1.0507009873554805f, SA = 1.6732632423543772f;
    float4 o;
    o.x = v.x * sc.x + sh.x;
    o.y = v.y * sc.y + sh.y;
    o.z = v.z * sc.z + sh.z;
    o.w = v.w * sc.w + sh.w;
    o.x = (o.x > 0.f) ? SL * o.x : SL * SA * expm1f(o.x);
    o.y = (o.y > 0.f) ? SL * o.y : SL * SA * expm1f(o.y);
    o.z = (o.z > 0.f) ? SL * o.z : SL * SA * expm1f(o.z);
    o.w = (o.w > 0.f) ? SL * o.w : SL * SA * expm1f(o.w);
    *(float4*)(outb + (size_t)gw * DIM + lane * 4) = o;
    float4 w = *(const float4*)(yw + lane * 4);
    float z = o.x * w.x + o.y * w.y + o.z * w.z + o.w * w.w;
#pragma unroll
    for (int off = 32; off > 0; off >>= 1) z += __shfl_xor(z, off);
    if (lane == 0) y[gw] = 1.f / (1.f + expf(-(z + yb[0])));
}

// ---------------- per-batch bitonic top-k (val desc, idx asc — jax semantics) ----------------
__global__ void k_topk(const float* __restrict__ y, float* __restrict__ svals,
                       int* __restrict__ sidx) {
    __shared__ float v[1024];
    __shared__ int  id[1024];
    int b = blockIdx.x, t = threadIdx.x;   // 512 threads
    v[t] = y[b * 1024 + t];           id[t] = t;
    v[t + 512] = y[b * 1024 + t + 512]; id[t + 512] = t + 512;
    __syncthreads();
    for (int k = 2; k <= 1024; k <<= 1) {
        for (int j = k >> 1; j > 0; j >>= 1) {
            for (int i = t; i < 1024; i += 512) {
                int l = i ^ j;
                if (l > i) {
                    float vi = v[i], vl = v[l];
                    int ii = id[i], il = id[l];
                    bool precede = (vi > vl) || (vi == vl && ii < il);
                    bool dirDesc = ((i & k) == 0);
                    bool sw = dirDesc ? !precede : precede;
                    if (sw) { v[i] = vl; v[l] = vi; id[i] = il; id[l] = ii; }
                }
            }
            __syncthreads();
        }
    }
    if (t < 512) { svals[b * 512 + t] = v[t]; sidx[b * 512 + t] = id[t]; }
}

// ---------------- gather + gate ----------------
__global__ void k_gather(const float* __restrict__ outb, const float* __restrict__ svals,
                         const int* __restrict__ sidx, float* __restrict__ dout) {
    int gw = (blockIdx.x * blockDim.x + threadIdx.x) >> 6;
    int lane = threadIdx.x & 63;
    int b = gw >> 9, r = gw & 511;
    float val = svals[b * 512 + r];
    int idn = sidx[b * 512 + r];
    float4 vv = *(const float4*)(outb + (size_t)(b * 1024 + idn) * DIM + lane * 4);
    vv.x *= val; vv.y *= val; vv.z *= val; vv.w *= val;
    *(float4*)(dout + (size_t)(b * 512 + r) * DIM + lane * 4) = vv;
}

extern "C" void kernel_launch(void* const* d_in, const int* in_sizes, int n_in,
                              void* d_out, int out_size, void* d_ws, size_t ws_size,
                              hipStream_t stream) {
    const float* x     = (const float*)d_in[0];
    const int* edges   = (const int*)d_in[1];
    const float* att_w = (const float*)d_in[2];
    const float* att_b = (const float*)d_in[3];
    const float* amap  = (const float*)d_in[4];
    const float* pwa_w = (const float*)d_in[5];
    const float* pwa_b = (const float*)d_in[6];
    const float* pwo_w = (const float*)d_in[7];
    const float* pwo_b = (const float*)d_in[8];
    const float* gamma = (const float*)d_in[9];
    const float* beta  = (const float*)d_in[10];
    const float* yw    = (const float*)d_in[11];
    const float* yb    = (const float*)d_in[12];
    float* out = (float*)d_out;
    const int* src = edges;
    const int* dst = edges + NEDGE;

    char* ws = (char*)d_ws;
    size_t off = 0;
    auto alloc = [&](size_t b) { void* p = ws + off; off = (off + b + 255) & ~(size_t)255; return p; };
    float* alpha  = (float*)alloc((size_t)NEDGE * 4);
    int*   elist  = (int*)alloc((size_t)NEDGE * 4);
    float* agg    = (float*)alloc((size_t)NODES * DIM * 4);
    float* outb   = (float*)alloc((size_t)NODES * DIM * 4);
    int*   deg    = (int*)alloc(NODES * 4);
    int*   rowptr = (int*)alloc((NODES + 1) * 4);
    int*   cursor = (int*)alloc(NODES * 4);
    double* psum  = (double*)alloc(32 * DIM * 8);
    double* psq   = (double*)alloc(32 * DIM * 8);
    float* scale  = (float*)alloc(DIM * 4);
    float* shift  = (float*)alloc(DIM * 4);
    float* yv     = (float*)alloc(NODES * 4);
    float* svals  = (float*)alloc(8 * 512 * 4);
    int*   sidx   = (int*)alloc(8 * 512 * 4);
    u16*   wf     = (u16*)alloc((size_t)16 * 4 * 4 * 512 * 2);

    k_wfrag<<<32, 256, 0, stream>>>(att_w, wf);
    k_zero<<<NODES / 256, 256, 0, stream>>>(deg);
    k_deg<<<NEDGE / 256, 256, 0, stream>>>(dst, deg);
    k_scan<<<1, 256, 0, stream>>>(deg, rowptr, cursor);
    k_fill<<<NEDGE / 256, 256, 0, stream>>>(dst, cursor, elist);
    k_alpha_v8<<<NEDGE / 64, 256, 0, stream>>>(x, src, dst, wf, att_b, amap, alpha);
    k_aggregate<<<NODES / 4, 256, 0, stream>>>(x, src, alpha, rowptr, elist, agg);
    k_out<<<NODES / 64, 256, 0, stream>>>(agg, x, pwa_w, pwo_w, pwa_b, pwo_b, outb);
    k_colstat<<<32, 256, 0, stream>>>(outb, psum, psq);
    k_bnparam<<<1, 256, 0, stream>>>(psum, psq, gamma, beta, scale, shift);
    k_bnselu<<<NODES / 4, 256, 0, stream>>>(outb, scale, shift, yw, yb, yv);
    k_topk<<<8, 512, 0, stream>>>(yv, svals, sidx);
    k_gather<<<(8 * 512) / 4, 256, 0, stream>>>(outb, svals, sidx, out);
}

// Round 9
// 337.732 us; speedup vs baseline: 1.2339x; 1.2195x over previous
//
#include <hip/hip_runtime.h>
#include <math.h>

#define NODES 8192
#define NEDGE 262144
#define DIM 256

typedef float f32x16 __attribute__((ext_vector_type(16)));
typedef _Float16 f16x8 __attribute__((ext_vector_type(8)));
typedef unsigned short u16;
typedef u16 u16x8 __attribute__((ext_vector_type(8)));
typedef u16 u16x4 __attribute__((ext_vector_type(4)));

__device__ __forceinline__ float fast_tanh(float x) {
    float t = __expf(2.f * x);
    return 1.f - 2.f * __builtin_amdgcn_rcpf(t + 1.f);
}

__device__ __forceinline__ u16 h_bits(_Float16 h) {
    u16 r; __builtin_memcpy(&r, &h, 2); return r;
}

// ---------------- CSR build (dst-indexed) ----------------
__global__ void k_zero(int* __restrict__ deg) {
    int i = blockIdx.x * blockDim.x + threadIdx.x;
    if (i < NODES) deg[i] = 0;
}

__global__ void k_deg(const int* __restrict__ dst, int* __restrict__ deg) {
    int e = blockIdx.x * blockDim.x + threadIdx.x;
    if (e < NEDGE) atomicAdd(&deg[dst[e]], 1);
}

__global__ void k_scan(const int* __restrict__ deg, int* __restrict__ rowptr,
                       int* __restrict__ cursor) {
    __shared__ int part[256];
    int t = threadIdx.x;
    int base = t * 32;
    int local[32];
    int s = 0;
    for (int i = 0; i < 32; ++i) { local[i] = s; s += deg[base + i]; }
    part[t] = s;
    __syncthreads();
    for (int off = 1; off < 256; off <<= 1) {
        int v = (t >= off) ? part[t - off] : 0;
        __syncthreads();
        part[t] += v;
        __syncthreads();
    }
    int excl = (t == 0) ? 0 : part[t - 1];
    for (int i = 0; i < 32; ++i) {
        int v = excl + local[i];
        rowptr[base + i] = v;
        cursor[base + i] = v;
    }
    if (t == 255) rowptr[NODES] = part[255];
}

__global__ void k_fill(const int* __restrict__ dst, int* __restrict__ cursor,
                       int* __restrict__ elist) {
    int e = blockIdx.x * blockDim.x + threadIdx.x;
    if (e < NEDGE) {
        int pos = atomicAdd(&cursor[dst[e]], 1);
        elist[pos] = e;
    }
}

// ---------------- W -> fp16 2-plane fragment order (plane2 pre-scaled 2^11) --
__global__ void k_wfrag(const float* __restrict__ W, u16* __restrict__ wf) {
    int t = blockIdx.x * blockDim.x + threadIdx.x;
    if (t >= 16 * 4 * 2 * 64) return;
    int lane = t & 63;
    int mt = (t >> 6) & 1;
    int w = (t >> 7) & 3;
    int gks = t >> 9;
    int row = w * 64 + mt * 32 + (lane & 31);
    int k0 = gks * 16 + (lane >> 5) * 8;
    const float* p = W + (size_t)row * DIM + k0;
    u16x8 v1, v2;
#pragma unroll
    for (int j = 0; j < 8; ++j) {
        float f = p[j];
        _Float16 h1 = (_Float16)f;
        float f1 = (float)h1;
        _Float16 h2 = (_Float16)((f - f1) * 2048.f);
        v1[j] = h_bits(h1);
        v2[j] = h_bits(h2);
    }
    size_t base = ((size_t)(gks * 4 + w) * 4 + mt * 2) * 512 + lane * 8;
    *(u16x8*)(wf + base)       = v1;
    *(u16x8*)(wf + base + 512) = v2;
}

// ---------------- alpha via fp16 2-split MFMA 32x32x16, v9 ----------------
// dst-grouped edges (elist order), cooperative 1KB row staging, flat k-major
// XOR-swizzled LDS, single barrier + 16-step MFMA burst. alpha written in
// elist-position order (coalesced consumption by k_aggregate).
__global__ __launch_bounds__(256, 2) void k_alpha_v9(
    const float* __restrict__ x, const int* __restrict__ srcv, const int* __restrict__ dstv,
    const int* __restrict__ elist, const u16* __restrict__ wf,
    const float* __restrict__ bias, const float* __restrict__ amap,
    float* __restrict__ alpha_pos)
{
    __shared__ u16 p_lds[2][64][256];   // 64 KB flat; [plane][edge][k], k-byte ^ ((edge&7)<<4)
    const int tid = threadIdx.x;
    const int w = tid >> 6;
    const int lane = tid & 63;
    const int l31 = lane & 31;
    const int g2 = lane >> 5;
    const int bid = blockIdx.x;
    const int wg = (bid & 7) * 512 + (bid >> 3);   // chunked XCD swizzle (4096%8==0)
    const int e0 = wg * 64;

    f32x16 accM[2][2], accC[2][2];
#pragma unroll
    for (int mt = 0; mt < 2; ++mt)
#pragma unroll
        for (int nt = 0; nt < 2; ++nt) { accM[mt][nt] = (f32x16)0.f; accC[mt][nt] = (f32x16)0.f; }

    f16x8 afA[2][2], afB[2][2];

#define PREFA(DST, GKS) { \
    const u16* pb = wf + ((size_t)((GKS) * 4 + w) * 4) * 512 + lane * 8; \
    _Pragma("unroll") for (int mt = 0; mt < 2; ++mt) \
    _Pragma("unroll") for (int pl = 0; pl < 2; ++pl) \
        DST[mt][pl] = *(const f16x8*)(const void*)(pb + (mt * 2 + pl) * 512); }

    PREFA(afA, 0)

    // ---- cooperative staging: wave w stages edges [16w, 16w+16) ----
    {
        const int ebase = e0 + w * 16;
#pragma unroll
        for (int i = 0; i < 16; ++i) {
            int e  = elist[ebase + i];
            int ns = srcv[e];
            int nd = dstv[e];
            float4 a = *(const float4*)(x + (size_t)ns * DIM + lane * 4);
            float4 b = *(const float4*)(x + (size_t)nd * DIM + lane * 4);
            float pv[4] = {a.x * b.x, a.y * b.y, a.z * b.z, a.w * b.w};
            u16x4 v1, v2;
#pragma unroll
            for (int j = 0; j < 4; ++j) {
                float f = pv[j];
                _Float16 h1 = (_Float16)f;
                float f1 = (float)h1;
                _Float16 h2 = (_Float16)((f - f1) * 2048.f);
                v1[j] = h_bits(h1);
                v2[j] = h_bits(h2);
            }
            const int le = w * 16 + i;
            const unsigned off = ((unsigned)(lane * 8)) ^ (((unsigned)(le & 7)) << 4);
            *(u16x4*)((char*)&p_lds[0][le][0] + off) = v1;
            *(u16x4*)((char*)&p_lds[1][le][0] + off) = v2;
        }
    }
    __syncthreads();

    // ---- 16-step MFMA burst (A ping-pong prefetch from wf) ----
    const unsigned swz = ((unsigned)(l31 & 7)) << 4;
#pragma unroll
    for (int gks = 0; gks < 16; ++gks) {
        if (gks + 1 < 16) {
            if (gks & 1) { PREFA(afA, gks + 1) } else { PREFA(afB, gks + 1) }
        }
        f16x8 bfr[2][2];
#pragma unroll
        for (int nt = 0; nt < 2; ++nt) {
            const int en = nt * 32 + l31;
            const unsigned off = ((unsigned)(gks * 32 + g2 * 16)) ^ swz;
#pragma unroll
            for (int pl = 0; pl < 2; ++pl)
                bfr[nt][pl] = *(const f16x8*)(const void*)((const char*)&p_lds[pl][en][0] + off);
        }
#pragma unroll
        for (int mt = 0; mt < 2; ++mt)
#pragma unroll
            for (int nt = 0; nt < 2; ++nt) {
                f16x8 a1 = (gks & 1) ? afB[mt][0] : afA[mt][0];
                f16x8 a2 = (gks & 1) ? afB[mt][1] : afA[mt][1];
                accM[mt][nt] = __builtin_amdgcn_mfma_f32_32x32x16_f16(a1, bfr[nt][0], accM[mt][nt], 0, 0, 0);
                accC[mt][nt] = __builtin_amdgcn_mfma_f32_32x32x16_f16(a1, bfr[nt][1], accC[mt][nt], 0, 0, 0);
                accC[mt][nt] = __builtin_amdgcn_mfma_f32_32x32x16_f16(a2, bfr[nt][0], accC[mt][nt], 0, 0, 0);
            }
    }
#undef PREFA

    // ---- epilogue: alpha = sum_out amap*tanh(h+bias), h = M + C*2^-11 ----
    float part[2] = {0.f, 0.f};
#pragma unroll
    for (int mt = 0; mt < 2; ++mt)
#pragma unroll
        for (int r = 0; r < 16; ++r) {
            int o = 64 * w + 32 * mt + (r & 3) + 8 * (r >> 2) + 4 * g2;
            float bo = bias[o], ao = amap[o];
#pragma unroll
            for (int nt = 0; nt < 2; ++nt) {
                float h = accM[mt][nt][r] + accC[mt][nt][r] * 4.8828125e-4f;
                part[nt] += ao * fast_tanh(h + bo);
            }
        }
    __syncthreads();                       // all LDS reads done; reuse p_lds for reduction
    float* red = (float*)(void*)p_lds;     // [4][64]
#pragma unroll
    for (int nt = 0; nt < 2; ++nt) {
        float p = part[nt];
        p += __shfl_xor(p, 32);
        if (lane < 32) red[w * 64 + nt * 32 + lane] = p;
    }
    __syncthreads();
    if (tid < 64) alpha_pos[e0 + tid] = red[tid] + red[64 + tid] + red[128 + tid] + red[192 + tid];
}

// ---------------- per-node segment softmax + weighted aggregate ----------------
// alpha_pos is in elist-position order -> coalesced reads.
__global__ void k_aggregate(
    const float* __restrict__ x, const int* __restrict__ src,
    const float* __restrict__ alpha_pos, const int* __restrict__ rowptr,
    const int* __restrict__ elist, float* __restrict__ agg)
{
    int gw = (blockIdx.x * blockDim.x + threadIdx.x) >> 6;
    int lane = threadIdx.x & 63;
    if (gw >= NODES) return;
    int start = rowptr[gw], end = rowptr[gw + 1];
    int deg = end - start;
    float m = -INFINITY;
    for (int i = lane; i < deg; i += 64) m = fmaxf(m, alpha_pos[start + i]);
#pragma unroll
    for (int off = 32; off > 0; off >>= 1) m = fmaxf(m, __shfl_xor(m, off));
    float ssum = 0.f;
    for (int i = lane; i < deg; i += 64) ssum += expf(alpha_pos[start + i] - m);
#pragma unroll
    for (int off = 32; off > 0; off >>= 1) ssum += __shfl_xor(ssum, off);
    float a0 = 0.f, a1 = 0.f, a2 = 0.f, a3 = 0.f;
    for (int i = 0; i < deg; ++i) {
        float wgt = expf(alpha_pos[start + i] - m);
        int e = elist[start + i];
        const float4 v = *(const float4*)(x + (size_t)src[e] * DIM + lane * 4);
        a0 += wgt * v.x; a1 += wgt * v.y; a2 += wgt * v.z; a3 += wgt * v.w;
    }
    float inv = 1.f / (ssum + 1e-16f);
    float4 r; r.x = a0 * inv; r.y = a1 * inv; r.z = a2 * inv; r.w = a3 * inv;
    *(float4*)(agg + (size_t)gw * DIM + lane * 4) = r;
}

// ---------------- out = agg@pwa^T + x@pwo^T + biases ----------------
__global__ __launch_bounds__(256, 2) void k_out(
    const float* __restrict__ agg, const float* __restrict__ x,
    const float* __restrict__ Wa, const float* __restrict__ Wo,
    const float* __restrict__ ba, const float* __restrict__ bo,
    float* __restrict__ outb)
{
    __shared__ float As[256][36];
    __shared__ float Bs[64][36];
    __shared__ float Cs[64][68];
    const int tid = threadIdx.x;
    const int oo = tid >> 3, ee = tid & 7;
    const int n0 = blockIdx.x * 64;
    const int bn = tid >> 2, bks = tid & 3;

    float acc[8][8];
#pragma unroll
    for (int j = 0; j < 8; ++j)
#pragma unroll
        for (int je = 0; je < 8; ++je) acc[j][je] = 0.f;

    for (int cc = 0; cc < 16; ++cc) {
        const float* Wsrc = (cc < 8) ? Wa : Wo;
        const float* Bsrc = (cc < 8) ? agg : x;
        const int kc = (cc & 7) * 32;
        {
            const float4* g = (const float4*)(Wsrc + (size_t)tid * DIM + kc);
            float4* l = (float4*)(&As[tid][0]);
#pragma unroll
            for (int i = 0; i < 8; ++i) l[i] = g[i];
        }
        {
            const float4* g = (const float4*)(Bsrc + (size_t)(n0 + bn) * DIM + kc + bks * 8);
            *(float4*)(&Bs[bn][bks * 8])     = g[0];
            *(float4*)(&Bs[bn][bks * 8 + 4]) = g[1];
        }
        __syncthreads();
#pragma unroll
        for (int kq = 0; kq < 8; ++kq) {
            float4 av[8], bv[8];
#pragma unroll
            for (int j = 0; j < 8; ++j)  av[j] = *(const float4*)(&As[oo + 32 * j][kq * 4]);
#pragma unroll
            for (int je = 0; je < 8; ++je) bv[je] = *(const float4*)(&Bs[ee + 8 * je][kq * 4]);
#pragma unroll
            for (int j = 0; j < 8; ++j)
#pragma unroll
                for (int je = 0; je < 8; ++je) {
                    acc[j][je] += av[j].x * bv[je].x;
                    acc[j][je] += av[j].y * bv[je].y;
                    acc[j][je] += av[j].z * bv[je].z;
                    acc[j][je] += av[j].w * bv[je].w;
                }
        }
        __syncthreads();
    }

    float bsum[8];
#pragma unroll
    for (int j = 0; j < 8; ++j) bsum[j] = ba[oo + 32 * j] + bo[oo + 32 * j];

    for (int c = 0; c < 4; ++c) {
#pragma unroll
        for (int jh = 0; jh < 2; ++jh) {
            int j = 2 * c + jh;
#pragma unroll
            for (int je = 0; je < 8; ++je)
                Cs[ee + 8 * je][oo + 32 * jh] = acc[j][je] + bsum[j];
        }
        __syncthreads();
        int ol = tid & 63, wv = tid >> 6;
        for (int r = wv; r < 64; r += 4)
            outb[(size_t)(n0 + r) * DIM + c * 64 + ol] = Cs[r][ol];
        __syncthreads();
    }
}

// ---------------- BN column stats (fp64 partials) ----------------
__global__ void k_colstat(const float* __restrict__ outb, double* __restrict__ psum,
                          double* __restrict__ psq) {
    int g = blockIdx.x, t = threadIdx.x;
    double s = 0.0, q = 0.0;
    const float* p = outb + (size_t)g * 256 * DIM + t;
    for (int r = 0; r < 256; ++r) { double v = (double)p[(size_t)r * DIM]; s += v; q += v * v; }
    psum[g * DIM + t] = s;
    psq[g * DIM + t] = q;
}

__global__ void k_bnparam(const double* __restrict__ psum, const double* __restrict__ psq,
                          const float* __restrict__ gamma, const float* __restrict__ beta,
                          float* __restrict__ scale, float* __restrict__ shift) {
    int t = threadIdx.x;
    double s = 0.0, q = 0.0;
    for (int g = 0; g < 32; ++g) { s += psum[g * DIM + t]; q += psq[g * DIM + t]; }
    double mean = s / (double)NODES;
    double var = q / (double)NODES - mean * mean;
    float sc = (float)((double)gamma[t] / sqrt(var + 1e-5));
    scale[t] = sc;
    shift[t] = (float)((double)beta[t] - mean * (double)sc);
}

// ---------------- affine + SELU + pooling score ----------------
__global__ void k_bnselu(float* __restrict__ outb, const float* __restrict__ scale,
                         const float* __restrict__ shift, const float* __restrict__ yw,
                         const float* __restrict__ yb, float* __restrict__ y) {
    int gw = (blockIdx.x * blockDim.x + threadIdx.x) >> 6;
    int lane = threadIdx.x & 63;
    if (gw >= NODES) return;
    float4 v  = *(const float4*)(outb + (size_t)gw * DIM + lane * 4);
    float4 sc = *(const float4*)(scale + lane * 4);
    float4 sh = *(const float4*)(shift + lane * 4);
    const float SL = 1.0507009873554805f, SA = 1.6732632423543772f;
    float4 o;
    o.x = v.x * sc.x + sh.x;
    o.y = v.y * sc.y + sh.y;
    o.z = v.z * sc.z + sh.z;
    o.w = v.w * sc.w + sh.w;
    o.x = (o.x > 0.f) ? SL * o.x : SL * SA * expm1f(o.x);
    o.y = (o.y > 0.f) ? SL * o.y : SL * SA * expm1f(o.y);
    o.z = (o.z > 0.f) ? SL * o.z : SL * SA * expm1f(o.z);
    o.w = (o.w > 0.f) ? SL * o.w : SL * SA * expm1f(o.w);
    *(float4*)(outb + (size_t)gw * DIM + lane * 4) = o;
    float4 w = *(const float4*)(yw + lane * 4);
    float z = o.x * w.x + o.y * w.y + o.z * w.z + o.w * w.w;
#pragma unroll
    for (int off = 32; off > 0; off >>= 1) z += __shfl_xor(z, off);
    if (lane == 0) y[gw] = 1.f / (1.f + expf(-(z + yb[0])));
}

// ---------------- per-batch bitonic top-k (val desc, idx asc — jax semantics) ----------------
__global__ void k_topk(const float* __restrict__ y, float* __restrict__ svals,
                       int* __restrict__ sidx) {
    __shared__ float v[1024];
    __shared__ int  id[1024];
    int b = blockIdx.x, t = threadIdx.x;   // 512 threads
    v[t] = y[b * 1024 + t];           id[t] = t;
    v[t + 512] = y[b * 1024 + t + 512]; id[t + 512] = t + 512;
    __syncthreads();
    for (int k = 2; k <= 1024; k <<= 1) {
        for (int j = k >> 1; j > 0; j >>= 1) {
            for (int i = t; i < 1024; i += 512) {
                int l = i ^ j;
                if (l > i) {
                    float vi = v[i], vl = v[l];
                    int ii = id[i], il = id[l];
                    bool precede = (vi > vl) || (vi == vl && ii < il);
                    bool dirDesc = ((i & k) == 0);
                    bool sw = dirDesc ? !precede : precede;
                    if (sw) { v[i] = vl; v[l] = vi; id[i] = il; id[l] = ii; }
                }
            }
            __syncthreads();
        }
    }
    if (t < 512) { svals[b * 512 + t] = v[t]; sidx[b * 512 + t] = id[t]; }
}

// ---------------- gather + gate ----------------
__global__ void k_gather(const float* __restrict__ outb, const float* __restrict__ svals,
                         const int* __restrict__ sidx, float* __restrict__ dout) {
    int gw = (blockIdx.x * blockDim.x + threadIdx.x) >> 6;
    int lane = threadIdx.x & 63;
    int b = gw >> 9, r = gw & 511;
    float val = svals[b * 512 + r];
    int idn = sidx[b * 512 + r];
    float4 vv = *(const float4*)(outb + (size_t)(b * 1024 + idn) * DIM + lane * 4);
    vv.x *= val; vv.y *= val; vv.z *= val; vv.w *= val;
    *(float4*)(dout + (size_t)(b * 512 + r) * DIM + lane * 4) = vv;
}

extern "C" void kernel_launch(void* const* d_in, const int* in_sizes, int n_in,
                              void* d_out, int out_size, void* d_ws, size_t ws_size,
                              hipStream_t stream) {
    const float* x     = (const float*)d_in[0];
    const int* edges   = (const int*)d_in[1];
    const float* att_w = (const float*)d_in[2];
    const float* att_b = (const float*)d_in[3];
    const float* amap  = (const float*)d_in[4];
    const float* pwa_w = (const float*)d_in[5];
    const float* pwa_b = (const float*)d_in[6];
    const float* pwo_w = (const float*)d_in[7];
    const float* pwo_b = (const float*)d_in[8];
    const float* gamma = (const float*)d_in[9];
    const float* beta  = (const float*)d_in[10];
    const float* yw    = (const float*)d_in[11];
    const float* yb    = (const float*)d_in[12];
    float* out = (float*)d_out;
    const int* src = edges;
    const int* dst = edges + NEDGE;

    char* ws = (char*)d_ws;
    size_t off = 0;
    auto alloc = [&](size_t b) { void* p = ws + off; off = (off + b + 255) & ~(size_t)255; return p; };
    float* alpha  = (float*)alloc((size_t)NEDGE * 4);      // elist-position order
    int*   elist  = (int*)alloc((size_t)NEDGE * 4);
    float* agg    = (float*)alloc((size_t)NODES * DIM * 4);
    float* outb   = (float*)alloc((size_t)NODES * DIM * 4);
    int*   deg    = (int*)alloc(NODES * 4);
    int*   rowptr = (int*)alloc((NODES + 1) * 4);
    int*   cursor = (int*)alloc(NODES * 4);
    double* psum  = (double*)alloc(32 * DIM * 8);
    double* psq   = (double*)alloc(32 * DIM * 8);
    float* scale  = (float*)alloc(DIM * 4);
    float* shift  = (float*)alloc(DIM * 4);
    float* yv     = (float*)alloc(NODES * 4);
    float* svals  = (float*)alloc(8 * 512 * 4);
    int*   sidx   = (int*)alloc(8 * 512 * 4);
    u16*   wf     = (u16*)alloc((size_t)16 * 4 * 4 * 512 * 2);

    k_wfrag<<<32, 256, 0, stream>>>(att_w, wf);
    k_zero<<<NODES / 256, 256, 0, stream>>>(deg);
    k_deg<<<NEDGE / 256, 256, 0, stream>>>(dst, deg);
    k_scan<<<1, 256, 0, stream>>>(deg, rowptr, cursor);
    k_fill<<<NEDGE / 256, 256, 0, stream>>>(dst, cursor, elist);
    k_alpha_v9<<<NEDGE / 64, 256, 0, stream>>>(x, src, dst, elist, wf, att_b, amap, alpha);
    k_aggregate<<<NODES / 4, 256, 0, stream>>>(x, src, alpha, rowptr, elist, agg);
    k_out<<<NODES / 64, 256, 0, stream>>>(agg, x, pwa_w, pwo_w, pwa_b, pwo_b, outb);
    k_colstat<<<32, 256, 0, stream>>>(outb, psum, psq);
    k_bnparam<<<1, 256, 0, stream>>>(psum, psq, gamma, beta, scale, shift);
    k_bnselu<<<NODES / 4, 256, 0, stream>>>(outb, scale, shift, yw, yb, yv);
    k_topk<<<8, 512, 0, stream>>>(yv, svals, sidx);
    k_gather<<<(8 * 512) / 4, 256, 0, stream>>>(outb, svals, sidx, out);
}

// Round 10
// 276.856 us; speedup vs baseline: 1.5052x; 1.2199x over previous
//
#include <hip/hip_runtime.h>
#include <math.h>

#define NODES 8192
#define NEDGE 262144
#define DIM 256

typedef float f32x16 __attribute__((ext_vector_type(16)));
typedef _Float16 f16x8 __attribute__((ext_vector_type(8)));
typedef unsigned short u16;
typedef u16 u16x8 __attribute__((ext_vector_type(8)));
typedef u16 u16x4 __attribute__((ext_vector_type(4)));
typedef u16 u16x2 __attribute__((ext_vector_type(2)));

__device__ __forceinline__ float fast_tanh(float x) {
    float t = __expf(2.f * x);
    return 1.f - 2.f * __builtin_amdgcn_rcpf(t + 1.f);
}

__device__ __forceinline__ u16 h_bits(_Float16 h) {
    u16 r; __builtin_memcpy(&r, &h, 2); return r;
}

// ---------------- CSR build (dst-indexed) ----------------
__global__ void k_zero(int* __restrict__ deg) {
    int i = blockIdx.x * blockDim.x + threadIdx.x;
    if (i < NODES) deg[i] = 0;
}

__global__ void k_deg(const int* __restrict__ dst, int* __restrict__ deg) {
    int e = blockIdx.x * blockDim.x + threadIdx.x;
    if (e < NEDGE) atomicAdd(&deg[dst[e]], 1);
}

__global__ void k_scan(const int* __restrict__ deg, int* __restrict__ rowptr,
                       int* __restrict__ cursor) {
    __shared__ int part[256];
    int t = threadIdx.x;
    int base = t * 32;
    int local[32];
    int s = 0;
    for (int i = 0; i < 32; ++i) { local[i] = s; s += deg[base + i]; }
    part[t] = s;
    __syncthreads();
    for (int off = 1; off < 256; off <<= 1) {
        int v = (t >= off) ? part[t - off] : 0;
        __syncthreads();
        part[t] += v;
        __syncthreads();
    }
    int excl = (t == 0) ? 0 : part[t - 1];
    for (int i = 0; i < 32; ++i) {
        int v = excl + local[i];
        rowptr[base + i] = v;
        cursor[base + i] = v;
    }
    if (t == 255) rowptr[NODES] = part[255];
}

// store (src,dst) pair at CSR position -> single-level indirection downstream
__global__ void k_fill(const int* __restrict__ src, const int* __restrict__ dst,
                       int* __restrict__ cursor, int2* __restrict__ sdg) {
    int e = blockIdx.x * blockDim.x + threadIdx.x;
    if (e < NEDGE) {
        int pos = atomicAdd(&cursor[dst[e]], 1);
        sdg[pos] = make_int2(src[e], dst[e]);
    }
}

// ---------------- att_w -> fp16 2-plane fragment order ----------------
__global__ void k_wfrag(const float* __restrict__ W, u16* __restrict__ wf) {
    int t = blockIdx.x * blockDim.x + threadIdx.x;
    if (t >= 16 * 4 * 2 * 64) return;
    int lane = t & 63;
    int mt = (t >> 6) & 1;
    int w = (t >> 7) & 3;
    int gks = t >> 9;
    int row = w * 64 + mt * 32 + (lane & 31);
    int k0 = gks * 16 + (lane >> 5) * 8;
    const float* p = W + (size_t)row * DIM + k0;
    u16x8 v1, v2;
#pragma unroll
    for (int j = 0; j < 8; ++j) {
        float f = p[j];
        _Float16 h1 = (_Float16)f;
        _Float16 h2 = (_Float16)((f - (float)h1) * 2048.f);
        v1[j] = h_bits(h1);
        v2[j] = h_bits(h2);
    }
    size_t base = ((size_t)(gks * 4 + w) * 4 + mt * 2) * 512 + lane * 8;
    *(u16x8*)(wf + base)       = v1;
    *(u16x8*)(wf + base + 512) = v2;
}

// ---------------- [pwa_w ; pwo_w] -> fragment order, K=512 (gks 0..31) -----
__global__ void k_wfrag2(const float* __restrict__ Wa, const float* __restrict__ Wo,
                         u16* __restrict__ wf2) {
    int t = blockIdx.x * blockDim.x + threadIdx.x;
    if (t >= 32 * 4 * 2 * 64) return;
    int lane = t & 63;
    int mt = (t >> 6) & 1;
    int w = (t >> 7) & 3;
    int gks = t >> 9;                       // 0..31
    const float* W = (gks < 16) ? Wa : Wo;
    int row = w * 64 + mt * 32 + (lane & 31);
    int k0 = (gks & 15) * 16 + (lane >> 5) * 8;
    const float* p = W + (size_t)row * DIM + k0;
    u16x8 v1, v2;
#pragma unroll
    for (int j = 0; j < 8; ++j) {
        float f = p[j];
        _Float16 h1 = (_Float16)f;
        _Float16 h2 = (_Float16)((f - (float)h1) * 2048.f);
        v1[j] = h_bits(h1);
        v2[j] = h_bits(h2);
    }
    size_t base = ((size_t)(gks * 4 + w) * 4 + mt * 2) * 512 + lane * 8;
    *(u16x8*)(wf2 + base)       = v1;
    *(u16x8*)(wf2 + base + 512) = v2;
}

// ---------------- alpha, v10: k-phase pipelined staging ----------------
__global__ __launch_bounds__(256, 2) void k_alpha_v10(
    const float* __restrict__ x, const int2* __restrict__ sdg,
    const u16* __restrict__ wf, const float* __restrict__ bias,
    const float* __restrict__ amap, float* __restrict__ alpha_pos)
{
    __shared__ u16 p_lds[2][64][256];   // [plane][edge][k-u16], byte ^ ((edge&7)<<4)
    const int tid = threadIdx.x;
    const int w = tid >> 6;
    const int lane = tid & 63;
    const int l31 = lane & 31;
    const int g2 = lane >> 5;
    const int bid = blockIdx.x;
    const int wg = (bid & 7) * 512 + (bid >> 3);   // XCD swizzle (4096%8==0)
    const int e0 = wg * 64;
    const int ebase = e0 + w * 16;
    const unsigned swz = ((unsigned)(l31 & 7)) << 4;

    f32x16 accM[2][2], accC[2][2];
#pragma unroll
    for (int mt = 0; mt < 2; ++mt)
#pragma unroll
        for (int nt = 0; nt < 2; ++nt) { accM[mt][nt] = (f32x16)0.f; accC[mt][nt] = (f32x16)0.f; }

    f16x8 afA[2][2], afB[2][2];
    float2 raA[2], rbA[2], raB[2], rbB[2];

#define PREFA(DST, GKS) { \
    const u16* pb_ = wf + ((size_t)((GKS) * 4 + w) * 4) * 512 + lane * 8; \
    _Pragma("unroll") for (int mt_ = 0; mt_ < 2; ++mt_) \
    _Pragma("unroll") for (int pl_ = 0; pl_ < 2; ++pl_) \
        DST[mt_][pl_] = *(const f16x8*)(const void*)(pb_ + (mt_ * 2 + pl_) * 512); }

#define SLOAD(PH, G, RA, RB) { \
    int2 sd0_ = sdg[ebase + (G) * 2]; \
    int2 sd1_ = sdg[ebase + (G) * 2 + 1]; \
    RA[0] = *(const float2*)(x + (size_t)sd0_.x * DIM + (PH) * 128 + lane * 2); \
    RB[0] = *(const float2*)(x + (size_t)sd0_.y * DIM + (PH) * 128 + lane * 2); \
    RA[1] = *(const float2*)(x + (size_t)sd1_.x * DIM + (PH) * 128 + lane * 2); \
    RB[1] = *(const float2*)(x + (size_t)sd1_.y * DIM + (PH) * 128 + lane * 2); }

#define SWRITE(PH, G, RA, RB) { \
    _Pragma("unroll") for (int j_ = 0; j_ < 2; ++j_) { \
        const int le_ = w * 16 + (G) * 2 + j_; \
        float p0_ = RA[j_].x * RB[j_].x; \
        float p1_ = RA[j_].y * RB[j_].y; \
        _Float16 h10_ = (_Float16)p0_; \
        _Float16 h11_ = (_Float16)p1_; \
        _Float16 h20_ = (_Float16)((p0_ - (float)h10_) * 2048.f); \
        _Float16 h21_ = (_Float16)((p1_ - (float)h11_) * 2048.f); \
        u16x2 v1_, v2_; \
        v1_[0] = h_bits(h10_); v1_[1] = h_bits(h11_); \
        v2_[0] = h_bits(h20_); v2_[1] = h_bits(h21_); \
        const unsigned off_ = ((unsigned)((PH) * 256 + lane * 4)) ^ (((unsigned)(le_ & 7)) << 4); \
        *(u16x2*)((char*)&p_lds[0][le_][0] + off_) = v1_; \
        *(u16x2*)((char*)&p_lds[1][le_][0] + off_) = v2_; } }

#define KSTEP(GKS) { \
    if ((GKS) + 1 < 16) { \
        if ((GKS) & 1) { PREFA(afA, (GKS) + 1) } else { PREFA(afB, (GKS) + 1) } \
    } \
    f16x8 bfr[2][2]; \
    _Pragma("unroll") for (int nt_ = 0; nt_ < 2; ++nt_) { \
        const int en_ = nt_ * 32 + l31; \
        const unsigned off_ = ((unsigned)((GKS) * 32 + g2 * 16)) ^ swz; \
        _Pragma("unroll") for (int pl_ = 0; pl_ < 2; ++pl_) \
            bfr[nt_][pl_] = *(const f16x8*)(const void*)((const char*)&p_lds[pl_][en_][0] + off_); \
    } \
    _Pragma("unroll") for (int mt_ = 0; mt_ < 2; ++mt_) \
    _Pragma("unroll") for (int nt_ = 0; nt_ < 2; ++nt_) { \
        f16x8 a1_ = ((GKS) & 1) ? afB[mt_][0] : afA[mt_][0]; \
        f16x8 a2_ = ((GKS) & 1) ? afB[mt_][1] : afA[mt_][1]; \
        accM[mt_][nt_] = __builtin_amdgcn_mfma_f32_32x32x16_f16(a1_, bfr[nt_][0], accM[mt_][nt_], 0, 0, 0); \
        accC[mt_][nt_] = __builtin_amdgcn_mfma_f32_32x32x16_f16(a1_, bfr[nt_][1], accC[mt_][nt_], 0, 0, 0); \
        accC[mt_][nt_] = __builtin_amdgcn_mfma_f32_32x32x16_f16(a2_, bfr[nt_][0], accC[mt_][nt_], 0, 0, 0); } }

    // ---- phase 0 staging (pipelined pairs) ----
    PREFA(afA, 0)
    SLOAD(0, 0, raA, rbA)
    SLOAD(0, 1, raB, rbB)
    SWRITE(0, 0, raA, rbA)
    SLOAD(0, 2, raA, rbA)
    SWRITE(0, 1, raB, rbB)
    SLOAD(0, 3, raB, rbB)
    SWRITE(0, 2, raA, rbA)
    SLOAD(0, 4, raA, rbA)
    SWRITE(0, 3, raB, rbB)
    SLOAD(0, 5, raB, rbB)
    SWRITE(0, 4, raA, rbA)
    SLOAD(0, 6, raA, rbA)
    SWRITE(0, 5, raB, rbB)
    SLOAD(0, 7, raB, rbB)
    SWRITE(0, 6, raA, rbA)
    SWRITE(0, 7, raB, rbB)
    __syncthreads();

    // ---- burst 0..7 with phase-1 staging interleaved ----
    SLOAD(1, 0, raA, rbA)
    KSTEP(0)
    SLOAD(1, 1, raB, rbB)
    SWRITE(1, 0, raA, rbA)
    KSTEP(1)
    SLOAD(1, 2, raA, rbA)
    SWRITE(1, 1, raB, rbB)
    KSTEP(2)
    SLOAD(1, 3, raB, rbB)
    SWRITE(1, 2, raA, rbA)
    KSTEP(3)
    SLOAD(1, 4, raA, rbA)
    SWRITE(1, 3, raB, rbB)
    KSTEP(4)
    SLOAD(1, 5, raB, rbB)
    SWRITE(1, 4, raA, rbA)
    KSTEP(5)
    SLOAD(1, 6, raA, rbA)
    SWRITE(1, 5, raB, rbB)
    KSTEP(6)
    SLOAD(1, 7, raB, rbB)
    SWRITE(1, 6, raA, rbA)
    KSTEP(7)
    SWRITE(1, 7, raB, rbB)
    __syncthreads();
    KSTEP(8)
    KSTEP(9)
    KSTEP(10)
    KSTEP(11)
    KSTEP(12)
    KSTEP(13)
    KSTEP(14)
    KSTEP(15)
#undef SLOAD
#undef SWRITE
#undef KSTEP
#undef PREFA

    // ---- epilogue: alpha = sum_out amap*tanh(h+bias), h = M + C*2^-11 ----
    float part[2] = {0.f, 0.f};
#pragma unroll
    for (int mt = 0; mt < 2; ++mt)
#pragma unroll
        for (int r = 0; r < 16; ++r) {
            int o = 64 * w + 32 * mt + (r & 3) + 8 * (r >> 2) + 4 * g2;
            float bo = bias[o], ao = amap[o];
#pragma unroll
            for (int nt = 0; nt < 2; ++nt) {
                float h = accM[mt][nt][r] + accC[mt][nt][r] * 4.8828125e-4f;
                part[nt] += ao * fast_tanh(h + bo);
            }
        }
    __syncthreads();
    float* red = (float*)(void*)p_lds;
#pragma unroll
    for (int nt = 0; nt < 2; ++nt) {
        float p = part[nt];
        p += __shfl_xor(p, 32);
        if (lane < 32) red[w * 64 + nt * 32 + lane] = p;
    }
    __syncthreads();
    if (tid < 64) alpha_pos[e0 + tid] = red[tid] + red[64 + tid] + red[128 + tid] + red[192 + tid];
}

// ---------------- segment softmax + weighted aggregate (unroll-4) ----------
__global__ void k_aggregate(
    const float* __restrict__ x, const float* __restrict__ alpha_pos,
    const int* __restrict__ rowptr, const int2* __restrict__ sdg,
    float* __restrict__ agg)
{
    int gw = (blockIdx.x * blockDim.x + threadIdx.x) >> 6;
    int lane = threadIdx.x & 63;
    if (gw >= NODES) return;
    int start = rowptr[gw], end = rowptr[gw + 1];
    int deg = end - start;
    float m = -INFINITY;
    for (int i = lane; i < deg; i += 64) m = fmaxf(m, alpha_pos[start + i]);
#pragma unroll
    for (int off = 32; off > 0; off >>= 1) m = fmaxf(m, __shfl_xor(m, off));
    float ssum = 0.f;
    for (int i = lane; i < deg; i += 64) ssum += expf(alpha_pos[start + i] - m);
#pragma unroll
    for (int off = 32; off > 0; off >>= 1) ssum += __shfl_xor(ssum, off);
    float a0 = 0.f, a1 = 0.f, a2 = 0.f, a3 = 0.f;
    int i = 0;
    for (; i + 4 <= deg; i += 4) {
        float w0 = expf(alpha_pos[start + i]     - m);
        float w1 = expf(alpha_pos[start + i + 1] - m);
        float w2 = expf(alpha_pos[start + i + 2] - m);
        float w3 = expf(alpha_pos[start + i + 3] - m);
        int r0 = sdg[start + i].x;
        int r1 = sdg[start + i + 1].x;
        int r2 = sdg[start + i + 2].x;
        int r3 = sdg[start + i + 3].x;
        float4 v0 = *(const float4*)(x + (size_t)r0 * DIM + lane * 4);
        float4 v1 = *(const float4*)(x + (size_t)r1 * DIM + lane * 4);
        float4 v2 = *(const float4*)(x + (size_t)r2 * DIM + lane * 4);
        float4 v3 = *(const float4*)(x + (size_t)r3 * DIM + lane * 4);
        a0 += w0 * v0.x + w1 * v1.x + w2 * v2.x + w3 * v3.x;
        a1 += w0 * v0.y + w1 * v1.y + w2 * v2.y + w3 * v3.y;
        a2 += w0 * v0.z + w1 * v1.z + w2 * v2.z + w3 * v3.z;
        a3 += w0 * v0.w + w1 * v1.w + w2 * v2.w + w3 * v3.w;
    }
    for (; i < deg; ++i) {
        float wgt = expf(alpha_pos[start + i] - m);
        int r = sdg[start + i].x;
        const float4 v = *(const float4*)(x + (size_t)r * DIM + lane * 4);
        a0 += wgt * v.x; a1 += wgt * v.y; a2 += wgt * v.z; a3 += wgt * v.w;
    }
    float inv = 1.f / (ssum + 1e-16f);
    float4 r; r.x = a0 * inv; r.y = a1 * inv; r.z = a2 * inv; r.w = a3 * inv;
    *(float4*)(agg + (size_t)gw * DIM + lane * 4) = r;
}

// ---------------- out = [agg|x] @ [Wa;Wo]^T + biases, MFMA 2-split ---------
__global__ __launch_bounds__(256, 2) void k_out_mfma(
    const float* __restrict__ agg, const float* __restrict__ x,
    const u16* __restrict__ wf2, const float* __restrict__ ba,
    const float* __restrict__ bo, float* __restrict__ outb)
{
    __shared__ u16 p_lds[2][64][256];       // 64 KB; reused as float Cs[64][256]
    const int tid = threadIdx.x;
    const int w = tid >> 6;
    const int lane = tid & 63;
    const int l31 = lane & 31;
    const int g2 = lane >> 5;
    const int n0 = blockIdx.x * 64;
    const unsigned swz = ((unsigned)(l31 & 7)) << 4;

    f32x16 accM[2][2], accC[2][2];
#pragma unroll
    for (int mt = 0; mt < 2; ++mt)
#pragma unroll
        for (int nt = 0; nt < 2; ++nt) { accM[mt][nt] = (f32x16)0.f; accC[mt][nt] = (f32x16)0.f; }

    f16x8 afA[2][2], afB[2][2];

#define PREFA2(DST, GKS) { \
    const u16* pb_ = wf2 + ((size_t)((GKS) * 4 + w) * 4) * 512 + lane * 8; \
    _Pragma("unroll") for (int mt_ = 0; mt_ < 2; ++mt_) \
    _Pragma("unroll") for (int pl_ = 0; pl_ < 2; ++pl_) \
        DST[mt_][pl_] = *(const f16x8*)(const void*)(pb_ + (mt_ * 2 + pl_) * 512); }

#define OSTAGE(SRC) { \
    _Pragma("unroll") for (int i_ = 0; i_ < 16; ++i_) { \
        const int ln_ = w * 16 + i_; \
        float4 v_ = *(const float4*)((SRC) + (size_t)(n0 + ln_) * DIM + lane * 4); \
        float pv_[4] = {v_.x, v_.y, v_.z, v_.w}; \
        u16x4 v1_, v2_; \
        _Pragma("unroll") for (int j_ = 0; j_ < 4; ++j_) { \
            float f_ = pv_[j_]; \
            _Float16 h1_ = (_Float16)f_; \
            _Float16 h2_ = (_Float16)((f_ - (float)h1_) * 2048.f); \
            v1_[j_] = h_bits(h1_); v2_[j_] = h_bits(h2_); } \
        const unsigned off_ = ((unsigned)(lane * 8)) ^ (((unsigned)(ln_ & 7)) << 4); \
        *(u16x4*)((char*)&p_lds[0][ln_][0] + off_) = v1_; \
        *(u16x4*)((char*)&p_lds[1][ln_][0] + off_) = v2_; } }

#define OKSTEP(GKS) { \
    if ((GKS) + 1 < 32) { \
        if ((GKS) & 1) { PREFA2(afA, (GKS) + 1) } else { PREFA2(afB, (GKS) + 1) } \
    } \
    f16x8 bfr[2][2]; \
    _Pragma("unroll") for (int nt_ = 0; nt_ < 2; ++nt_) { \
        const int en_ = nt_ * 32 + l31; \
        const unsigned off_ = ((unsigned)(((GKS) & 15) * 32 + g2 * 16)) ^ swz; \
        _Pragma("unroll") for (int pl_ = 0; pl_ < 2; ++pl_) \
            bfr[nt_][pl_] = *(const f16x8*)(const void*)((const char*)&p_lds[pl_][en_][0] + off_); \
    } \
    _Pragma("unroll") for (int mt_ = 0; mt_ < 2; ++mt_) \
    _Pragma("unroll") for (int nt_ = 0; nt_ < 2; ++nt_) { \
        f16x8 a1_ = ((GKS) & 1) ? afB[mt_][0] : afA[mt_][0]; \
        f16x8 a2_ = ((GKS) & 1) ? afB[mt_][1] : afA[mt_][1]; \
        accM[mt_][nt_] = __builtin_amdgcn_mfma_f32_32x32x16_f16(a1_, bfr[nt_][0], accM[mt_][nt_], 0, 0, 0); \
        accC[mt_][nt_] = __builtin_amdgcn_mfma_f32_32x32x16_f16(a1_, bfr[nt_][1], accC[mt_][nt_], 0, 0, 0); \
        accC[mt_][nt_] = __builtin_amdgcn_mfma_f32_32x32x16_f16(a2_, bfr[nt_][0], accC[mt_][nt_], 0, 0, 0); } }

    PREFA2(afA, 0)
    OSTAGE(agg)
    __syncthreads();
    OKSTEP(0)  OKSTEP(1)  OKSTEP(2)  OKSTEP(3)
    OKSTEP(4)  OKSTEP(5)  OKSTEP(6)  OKSTEP(7)
    OKSTEP(8)  OKSTEP(9)  OKSTEP(10) OKSTEP(11)
    OKSTEP(12) OKSTEP(13) OKSTEP(14) OKSTEP(15)
    __syncthreads();
    OSTAGE(x)
    __syncthreads();
    OKSTEP(16) OKSTEP(17) OKSTEP(18) OKSTEP(19)
    OKSTEP(20) OKSTEP(21) OKSTEP(22) OKSTEP(23)
    OKSTEP(24) OKSTEP(25) OKSTEP(26) OKSTEP(27)
    OKSTEP(28) OKSTEP(29) OKSTEP(30) OKSTEP(31)
#undef OSTAGE
#undef OKSTEP
#undef PREFA2

    // ---- epilogue: bias add + LDS transpose + coalesced store ----
    __syncthreads();
    float* Cs = (float*)(void*)p_lds;       // logical [64 nodes][256 outs], swizzled
#pragma unroll
    for (int mt = 0; mt < 2; ++mt)
#pragma unroll
        for (int r = 0; r < 16; ++r) {
            int o = 64 * w + 32 * mt + (r & 3) + 8 * (r >> 2) + 4 * g2;
            float bs = ba[o] + bo[o];
#pragma unroll
            for (int nt = 0; nt < 2; ++nt) {
                int col = nt * 32 + l31;
                float hv = accM[mt][nt][r] + accC[mt][nt][r] * 4.8828125e-4f + bs;
                unsigned ob = ((unsigned)(col * 1024 + o * 4)) ^ (((unsigned)(col & 31)) << 4);
                *(float*)((char*)Cs + ob) = hv;
            }
        }
    __syncthreads();
#pragma unroll
    for (int i = 0; i < 16; ++i) {
        int ln = w * 16 + i;
        unsigned rb = ((unsigned)(ln * 1024 + lane * 16)) ^ (((unsigned)(ln & 31)) << 4);
        float4 val = *(const float4*)((const char*)Cs + rb);
        *(float4*)(outb + (size_t)(n0 + ln) * DIM + lane * 4) = val;
    }
}

// ---------------- BN column stats (fp64 partials) ----------------
__global__ void k_colstat(const float* __restrict__ outb, double* __restrict__ psum,
                          double* __restrict__ psq) {
    int g = blockIdx.x, t = threadIdx.x;
    double s = 0.0, q = 0.0;
    const float* p = outb + (size_t)g * 256 * DIM + t;
    for (int r = 0; r < 256; ++r) { double v = (double)p[(size_t)r * DIM]; s += v; q += v * v; }
    psum[g * DIM + t] = s;
    psq[g * DIM + t] = q;
}

__global__ void k_bnparam(const double* __restrict__ psum, const double* __restrict__ psq,
                          const float* __restrict__ gamma, const float* __restrict__ beta,
                          float* __restrict__ scale, float* __restrict__ shift) {
    int t = threadIdx.x;
    double s = 0.0, q = 0.0;
    for (int g = 0; g < 32; ++g) { s += psum[g * DIM + t]; q += psq[g * DIM + t]; }
    double mean = s / (double)NODES;
    double var = q / (double)NODES - mean * mean;
    float sc = (float)((double)gamma[t] / sqrt(var + 1e-5));
    scale[t] = sc;
    shift[t] = (float)((double)beta[t] - mean * (double)sc);
}

// ---------------- affine + SELU + pooling score ----------------
__global__ void k_bnselu(float* __restrict__ outb, const float* __restrict__ scale,
                         const float* __restrict__ shift, const float* __restrict__ yw,
                         const float* __restrict__ yb, float* __restrict__ y) {
    int gw = (blockIdx.x * blockDim.x + threadIdx.x) >> 6;
    int lane = threadIdx.x & 63;
    if (gw >= NODES) return;
    float4 v  = *(const float4*)(outb + (size_t)gw * DIM + lane * 4);
    float4 sc = *(const float4*)(scale + lane * 4);
    float4 sh = *(const float4*)(shift + lane * 4);
    const float SL = 1.0507009873554805f, SA = 1.6732632423543772f;
    float4 o;
    o.x = v.x * sc.x + sh.x;
    o.y = v.y * sc.y + sh.y;
    o.z = v.z * sc.z + sh.z;
    o.w = v.w * sc.w + sh.w;
    o.x = (o.x > 0.f) ? SL * o.x : SL * SA * expm1f(o.x);
    o.y = (o.y > 0.f) ? SL * o.y : SL * SA * expm1f(o.y);
    o.z = (o.z > 0.f) ? SL * o.z : SL * SA * expm1f(o.z);
    o.w = (o.w > 0.f) ? SL * o.w : SL * SA * expm1f(o.w);
    *(float4*)(outb + (size_t)gw * DIM + lane * 4) = o;
    float4 w = *(const float4*)(yw + lane * 4);
    float z = o.x * w.x + o.y * w.y + o.z * w.z + o.w * w.w;
#pragma unroll
    for (int off = 32; off > 0; off >>= 1) z += __shfl_xor(z, off);
    if (lane == 0) y[gw] = 1.f / (1.f + expf(-(z + yb[0])));
}

// ---------------- per-batch bitonic top-k (val desc, idx asc) ----------------
__global__ void k_topk(const float* __restrict__ y, float* __restrict__ svals,
                       int* __restrict__ sidx) {
    __shared__ float v[1024];
    __shared__ int  id[1024];
    int b = blockIdx.x, t = threadIdx.x;   // 512 threads
    v[t] = y[b * 1024 + t];           id[t] = t;
    v[t + 512] = y[b * 1024 + t + 512]; id[t + 512] = t + 512;
    __syncthreads();
    for (int k = 2; k <= 1024; k <<= 1) {
        for (int j = k >> 1; j > 0; j >>= 1) {
            for (int i = t; i < 1024; i += 512) {
                int l = i ^ j;
                if (l > i) {
                    float vi = v[i], vl = v[l];
                    int ii = id[i], il = id[l];
                    bool precede = (vi > vl) || (vi == vl && ii < il);
                    bool dirDesc = ((i & k) == 0);
                    bool sw = dirDesc ? !precede : precede;
                    if (sw) { v[i] = vl; v[l] = vi; id[i] = il; id[l] = ii; }
                }
            }
            __syncthreads();
        }
    }
    if (t < 512) { svals[b * 512 + t] = v[t]; sidx[b * 512 + t] = id[t]; }
}

// ---------------- gather + gate ----------------
__global__ void k_gather(const float* __restrict__ outb, const float* __restrict__ svals,
                         const int* __restrict__ sidx, float* __restrict__ dout) {
    int gw = (blockIdx.x * blockDim.x + threadIdx.x) >> 6;
    int lane = threadIdx.x & 63;
    int b = gw >> 9, r = gw & 511;
    float val = svals[b * 512 + r];
    int idn = sidx[b * 512 + r];
    float4 vv = *(const float4*)(outb + (size_t)(b * 1024 + idn) * DIM + lane * 4);
    vv.x *= val; vv.y *= val; vv.z *= val; vv.w *= val;
    *(float4*)(dout + (size_t)(b * 512 + r) * DIM + lane * 4) = vv;
}

extern "C" void kernel_launch(void* const* d_in, const int* in_sizes, int n_in,
                              void* d_out, int out_size, void* d_ws, size_t ws_size,
                              hipStream_t stream) {
    const float* x     = (const float*)d_in[0];
    const int* edges   = (const int*)d_in[1];
    const float* att_w = (const float*)d_in[2];
    const float* att_b = (const float*)d_in[3];
    const float* amap  = (const float*)d_in[4];
    const float* pwa_w = (const float*)d_in[5];
    const float* pwa_b = (const float*)d_in[6];
    const float* pwo_w = (const float*)d_in[7];
    const float* pwo_b = (const float*)d_in[8];
    const float* gamma = (const float*)d_in[9];
    const float* beta  = (const float*)d_in[10];
    const float* yw    = (const float*)d_in[11];
    const float* yb    = (const float*)d_in[12];
    float* out = (float*)d_out;
    const int* src = edges;
    const int* dst = edges + NEDGE;

    char* ws = (char*)d_ws;
    size_t off = 0;
    auto alloc = [&](size_t b) { void* p = ws + off; off = (off + b + 255) & ~(size_t)255; return p; };
    float* alpha  = (float*)alloc((size_t)NEDGE * 4);      // CSR-position order
    int2*  sdg    = (int2*)alloc((size_t)NEDGE * 8);       // (src,dst) per CSR position
    float* agg    = (float*)alloc((size_t)NODES * DIM * 4);
    float* outb   = (float*)alloc((size_t)NODES * DIM * 4);
    int*   deg    = (int*)alloc(NODES * 4);
    int*   rowptr = (int*)alloc((NODES + 1) * 4);
    int*   cursor = (int*)alloc(NODES * 4);
    double* psum  = (double*)alloc(32 * DIM * 8);
    double* psq   = (double*)alloc(32 * DIM * 8);
    float* scale  = (float*)alloc(DIM * 4);
    float* shift  = (float*)alloc(DIM * 4);
    float* yv     = (float*)alloc(NODES * 4);
    float* svals  = (float*)alloc(8 * 512 * 4);
    int*   sidx   = (int*)alloc(8 * 512 * 4);
    u16*   wf     = (u16*)alloc((size_t)16 * 4 * 4 * 512 * 2);
    u16*   wf2    = (u16*)alloc((size_t)32 * 4 * 4 * 512 * 2);

    k_wfrag<<<32, 256, 0, stream>>>(att_w, wf);
    k_wfrag2<<<64, 256, 0, stream>>>(pwa_w, pwo_w, wf2);
    k_zero<<<NODES / 256, 256, 0, stream>>>(deg);
    k_deg<<<NEDGE / 256, 256, 0, stream>>>(dst, deg);
    k_scan<<<1, 256, 0, stream>>>(deg, rowptr, cursor);
    k_fill<<<NEDGE / 256, 256, 0, stream>>>(src, dst, cursor, sdg);
    k_alpha_v10<<<NEDGE / 64, 256, 0, stream>>>(x, sdg, wf, att_b, amap, alpha);
    k_aggregate<<<NODES / 4, 256, 0, stream>>>(x, alpha, rowptr, sdg, agg);
    k_out_mfma<<<NODES / 64, 256, 0, stream>>>(agg, x, wf2, pwa_b, pwo_b, outb);
    k_colstat<<<32, 256, 0, stream>>>(outb, psum, psq);
    k_bnparam<<<1, 256, 0, stream>>>(psum, psq, gamma, beta, scale, shift);
    k_bnselu<<<NODES / 4, 256, 0, stream>>>(outb, scale, shift, yw, yb, yv);
    k_topk<<<8, 512, 0, stream>>>(yv, svals, sidx);
    k_gather<<<(8 * 512) / 4, 256, 0, stream>>>(outb, svals, sidx, out);
}

// Round 11
// 274.773 us; speedup vs baseline: 1.5166x; 1.0076x over previous
//
#include <hip/hip_runtime.h>
#include <math.h>

#define NODES 8192
#define NEDGE 262144
#define DIM 256

typedef float f32x16 __attribute__((ext_vector_type(16)));
typedef _Float16 f16x8 __attribute__((ext_vector_type(8)));
typedef unsigned short u16;
typedef u16 u16x8 __attribute__((ext_vector_type(8)));
typedef u16 u16x4 __attribute__((ext_vector_type(4)));
typedef u16 u16x2 __attribute__((ext_vector_type(2)));

__device__ __forceinline__ float fast_tanh(float x) {
    float t = __expf(2.f * x);
    return 1.f - 2.f * __builtin_amdgcn_rcpf(t + 1.f);
}

__device__ __forceinline__ u16 h_bits(_Float16 h) {
    u16 r; __builtin_memcpy(&r, &h, 2); return r;
}

// ---------------- CSR build (dst-indexed) ----------------
__global__ void k_zero(int* __restrict__ deg) {
    int i = blockIdx.x * blockDim.x + threadIdx.x;
    if (i < NODES) deg[i] = 0;
}

__global__ void k_deg(const int* __restrict__ dst, int* __restrict__ deg) {
    int e = blockIdx.x * blockDim.x + threadIdx.x;
    if (e < NEDGE) atomicAdd(&deg[dst[e]], 1);
}

__global__ void k_scan(const int* __restrict__ deg, int* __restrict__ rowptr,
                       int* __restrict__ cursor) {
    __shared__ int part[256];
    int t = threadIdx.x;
    int base = t * 32;
    int local[32];
    int s = 0;
    for (int i = 0; i < 32; ++i) { local[i] = s; s += deg[base + i]; }
    part[t] = s;
    __syncthreads();
    for (int off = 1; off < 256; off <<= 1) {
        int v = (t >= off) ? part[t - off] : 0;
        __syncthreads();
        part[t] += v;
        __syncthreads();
    }
    int excl = (t == 0) ? 0 : part[t - 1];
    for (int i = 0; i < 32; ++i) {
        int v = excl + local[i];
        rowptr[base + i] = v;
        cursor[base + i] = v;
    }
    if (t == 255) rowptr[NODES] = part[255];
}

// store (src,dst) pair at CSR position -> single-level indirection downstream
__global__ void k_fill(const int* __restrict__ src, const int* __restrict__ dst,
                       int* __restrict__ cursor, int2* __restrict__ sdg) {
    int e = blockIdx.x * blockDim.x + threadIdx.x;
    if (e < NEDGE) {
        int pos = atomicAdd(&cursor[dst[e]], 1);
        sdg[pos] = make_int2(src[e], dst[e]);
    }
}

// ---------------- att_w -> fp16 2-plane fragment order ----------------
__global__ void k_wfrag(const float* __restrict__ W, u16* __restrict__ wf) {
    int t = blockIdx.x * blockDim.x + threadIdx.x;
    if (t >= 16 * 4 * 2 * 64) return;
    int lane = t & 63;
    int mt = (t >> 6) & 1;
    int w = (t >> 7) & 3;
    int gks = t >> 9;
    int row = w * 64 + mt * 32 + (lane & 31);
    int k0 = gks * 16 + (lane >> 5) * 8;
    const float* p = W + (size_t)row * DIM + k0;
    u16x8 v1, v2;
#pragma unroll
    for (int j = 0; j < 8; ++j) {
        float f = p[j];
        _Float16 h1 = (_Float16)f;
        _Float16 h2 = (_Float16)((f - (float)h1) * 2048.f);
        v1[j] = h_bits(h1);
        v2[j] = h_bits(h2);
    }
    size_t base = ((size_t)(gks * 4 + w) * 4 + mt * 2) * 512 + lane * 8;
    *(u16x8*)(wf + base)       = v1;
    *(u16x8*)(wf + base + 512) = v2;
}

// ---------------- [pwa_w ; pwo_w] -> fragment order, K=512 (gks 0..31) -----
__global__ void k_wfrag2(const float* __restrict__ Wa, const float* __restrict__ Wo,
                         u16* __restrict__ wf2) {
    int t = blockIdx.x * blockDim.x + threadIdx.x;
    if (t >= 32 * 4 * 2 * 64) return;
    int lane = t & 63;
    int mt = (t >> 6) & 1;
    int w = (t >> 7) & 3;
    int gks = t >> 9;                       // 0..31
    const float* W = (gks < 16) ? Wa : Wo;
    int row = w * 64 + mt * 32 + (lane & 31);
    int k0 = (gks & 15) * 16 + (lane >> 5) * 8;
    const float* p = W + (size_t)row * DIM + k0;
    u16x8 v1, v2;
#pragma unroll
    for (int j = 0; j < 8; ++j) {
        float f = p[j];
        _Float16 h1 = (_Float16)f;
        _Float16 h2 = (_Float16)((f - (float)h1) * 2048.f);
        v1[j] = h_bits(h1);
        v2[j] = h_bits(h2);
    }
    size_t base = ((size_t)(gks * 4 + w) * 4 + mt * 2) * 512 + lane * 8;
    *(u16x8*)(wf2 + base)       = v1;
    *(u16x8*)(wf2 + base + 512) = v2;
}

// ---------------- alpha, v11: 32 KB LDS (K phase-split) -> 4 blocks/CU ------
__global__ __launch_bounds__(256, 2) void k_alpha_v11(
    const float* __restrict__ x, const int2* __restrict__ sdg,
    const u16* __restrict__ wf, const float* __restrict__ bias,
    const float* __restrict__ amap, float* __restrict__ alpha_pos)
{
    __shared__ u16 p_lds[2][64][128];   // 32 KB; [plane][edge][k-half u16], byte ^ ((edge&7)<<4)
    const int tid = threadIdx.x;
    const int w = tid >> 6;
    const int lane = tid & 63;
    const int l31 = lane & 31;
    const int g2 = lane >> 5;
    const int bid = blockIdx.x;
    const int wg = (bid & 7) * 512 + (bid >> 3);   // XCD swizzle (4096%8==0)
    const int e0 = wg * 64;
    const int ebase = e0 + w * 16;
    const unsigned swz = ((unsigned)(l31 & 7)) << 4;

    f32x16 accM[2][2], accC[2][2];
#pragma unroll
    for (int mt = 0; mt < 2; ++mt)
#pragma unroll
        for (int nt = 0; nt < 2; ++nt) { accM[mt][nt] = (f32x16)0.f; accC[mt][nt] = (f32x16)0.f; }

    f16x8 afA[2][2], afB[2][2];

#define PREFA(DST, GKS) { \
    const u16* pb_ = wf + ((size_t)((GKS) * 4 + w) * 4) * 512 + lane * 8; \
    _Pragma("unroll") for (int mt_ = 0; mt_ < 2; ++mt_) \
    _Pragma("unroll") for (int pl_ = 0; pl_ < 2; ++pl_) \
        DST[mt_][pl_] = *(const f16x8*)(const void*)(pb_ + (mt_ * 2 + pl_) * 512); }

// stage this wave's 16 edges for k-range [PH*128, PH*128+128)
#define STAGE(PH) { \
    _Pragma("unroll") for (int i_ = 0; i_ < 16; ++i_) { \
        int2 sd_ = sdg[ebase + i_]; \
        float2 a_ = *(const float2*)(x + (size_t)sd_.x * DIM + (PH) * 128 + lane * 2); \
        float2 b_ = *(const float2*)(x + (size_t)sd_.y * DIM + (PH) * 128 + lane * 2); \
        float p0_ = a_.x * b_.x; \
        float p1_ = a_.y * b_.y; \
        _Float16 h10_ = (_Float16)p0_; \
        _Float16 h11_ = (_Float16)p1_; \
        _Float16 h20_ = (_Float16)((p0_ - (float)h10_) * 2048.f); \
        _Float16 h21_ = (_Float16)((p1_ - (float)h11_) * 2048.f); \
        u16x2 v1_, v2_; \
        v1_[0] = h_bits(h10_); v1_[1] = h_bits(h11_); \
        v2_[0] = h_bits(h20_); v2_[1] = h_bits(h21_); \
        const int le_ = w * 16 + i_; \
        const unsigned off_ = ((unsigned)(lane * 4)) ^ (((unsigned)(le_ & 7)) << 4); \
        *(u16x2*)((char*)&p_lds[0][le_][0] + off_) = v1_; \
        *(u16x2*)((char*)&p_lds[1][le_][0] + off_) = v2_; } }

#define KSTEP(GKS) { \
    if ((GKS) + 1 < 16) { \
        if ((GKS) & 1) { PREFA(afA, (GKS) + 1) } else { PREFA(afB, (GKS) + 1) } \
    } \
    f16x8 bfr[2][2]; \
    _Pragma("unroll") for (int nt_ = 0; nt_ < 2; ++nt_) { \
        const int en_ = nt_ * 32 + l31; \
        const unsigned off_ = ((unsigned)(((GKS) & 7) * 32 + g2 * 16)) ^ swz; \
        _Pragma("unroll") for (int pl_ = 0; pl_ < 2; ++pl_) \
            bfr[nt_][pl_] = *(const f16x8*)(const void*)((const char*)&p_lds[pl_][en_][0] + off_); \
    } \
    _Pragma("unroll") for (int mt_ = 0; mt_ < 2; ++mt_) \
    _Pragma("unroll") for (int nt_ = 0; nt_ < 2; ++nt_) { \
        f16x8 a1_ = ((GKS) & 1) ? afB[mt_][0] : afA[mt_][0]; \
        f16x8 a2_ = ((GKS) & 1) ? afB[mt_][1] : afA[mt_][1]; \
        accM[mt_][nt_] = __builtin_amdgcn_mfma_f32_32x32x16_f16(a1_, bfr[nt_][0], accM[mt_][nt_], 0, 0, 0); \
        accC[mt_][nt_] = __builtin_amdgcn_mfma_f32_32x32x16_f16(a1_, bfr[nt_][1], accC[mt_][nt_], 0, 0, 0); \
        accC[mt_][nt_] = __builtin_amdgcn_mfma_f32_32x32x16_f16(a2_, bfr[nt_][0], accC[mt_][nt_], 0, 0, 0); } }

    PREFA(afA, 0)
    STAGE(0)
    __syncthreads();
    KSTEP(0) KSTEP(1) KSTEP(2) KSTEP(3)
    KSTEP(4) KSTEP(5) KSTEP(6) KSTEP(7)
    __syncthreads();
    STAGE(1)
    __syncthreads();
    KSTEP(8)  KSTEP(9)  KSTEP(10) KSTEP(11)
    KSTEP(12) KSTEP(13) KSTEP(14) KSTEP(15)
#undef STAGE
#undef KSTEP
#undef PREFA

    // ---- epilogue: alpha = sum_out amap*tanh(h+bias), h = M + C*2^-11 ----
    float part[2] = {0.f, 0.f};
#pragma unroll
    for (int mt = 0; mt < 2; ++mt)
#pragma unroll
        for (int r = 0; r < 16; ++r) {
            int o = 64 * w + 32 * mt + (r & 3) + 8 * (r >> 2) + 4 * g2;
            float bo = bias[o], ao = amap[o];
#pragma unroll
            for (int nt = 0; nt < 2; ++nt) {
                float h = accM[mt][nt][r] + accC[mt][nt][r] * 4.8828125e-4f;
                part[nt] += ao * fast_tanh(h + bo);
            }
        }
    __syncthreads();
    float* red = (float*)(void*)p_lds;
#pragma unroll
    for (int nt = 0; nt < 2; ++nt) {
        float p = part[nt];
        p += __shfl_xor(p, 32);
        if (lane < 32) red[w * 64 + nt * 32 + lane] = p;
    }
    __syncthreads();
    if (tid < 64) alpha_pos[e0 + tid] = red[tid] + red[64 + tid] + red[128 + tid] + red[192 + tid];
}

// ---------------- segment softmax + weighted aggregate (unroll-4) ----------
__global__ void k_aggregate(
    const float* __restrict__ x, const float* __restrict__ alpha_pos,
    const int* __restrict__ rowptr, const int2* __restrict__ sdg,
    float* __restrict__ agg)
{
    int gw = (blockIdx.x * blockDim.x + threadIdx.x) >> 6;
    int lane = threadIdx.x & 63;
    if (gw >= NODES) return;
    int start = rowptr[gw], end = rowptr[gw + 1];
    int deg = end - start;
    float m = -INFINITY;
    for (int i = lane; i < deg; i += 64) m = fmaxf(m, alpha_pos[start + i]);
#pragma unroll
    for (int off = 32; off > 0; off >>= 1) m = fmaxf(m, __shfl_xor(m, off));
    float ssum = 0.f;
    for (int i = lane; i < deg; i += 64) ssum += expf(alpha_pos[start + i] - m);
#pragma unroll
    for (int off = 32; off > 0; off >>= 1) ssum += __shfl_xor(ssum, off);
    float a0 = 0.f, a1 = 0.f, a2 = 0.f, a3 = 0.f;
    int i = 0;
    for (; i + 4 <= deg; i += 4) {
        float w0 = expf(alpha_pos[start + i]     - m);
        float w1 = expf(alpha_pos[start + i + 1] - m);
        float w2 = expf(alpha_pos[start + i + 2] - m);
        float w3 = expf(alpha_pos[start + i + 3] - m);
        int r0 = sdg[start + i].x;
        int r1 = sdg[start + i + 1].x;
        int r2 = sdg[start + i + 2].x;
        int r3 = sdg[start + i + 3].x;
        float4 v0 = *(const float4*)(x + (size_t)r0 * DIM + lane * 4);
        float4 v1 = *(const float4*)(x + (size_t)r1 * DIM + lane * 4);
        float4 v2 = *(const float4*)(x + (size_t)r2 * DIM + lane * 4);
        float4 v3 = *(const float4*)(x + (size_t)r3 * DIM + lane * 4);
        a0 += w0 * v0.x + w1 * v1.x + w2 * v2.x + w3 * v3.x;
        a1 += w0 * v0.y + w1 * v1.y + w2 * v2.y + w3 * v3.y;
        a2 += w0 * v0.z + w1 * v1.z + w2 * v2.z + w3 * v3.z;
        a3 += w0 * v0.w + w1 * v1.w + w2 * v2.w + w3 * v3.w;
    }
    for (; i < deg; ++i) {
        float wgt = expf(alpha_pos[start + i] - m);
        int r = sdg[start + i].x;
        const float4 v = *(const float4*)(x + (size_t)r * DIM + lane * 4);
        a0 += wgt * v.x; a1 += wgt * v.y; a2 += wgt * v.z; a3 += wgt * v.w;
    }
    float inv = 1.f / (ssum + 1e-16f);
    float4 r; r.x = a0 * inv; r.y = a1 * inv; r.z = a2 * inv; r.w = a3 * inv;
    *(float4*)(agg + (size_t)gw * DIM + lane * 4) = r;
}

// ---------------- out = [agg|x] @ [Wa;Wo]^T + biases, MFMA 2-split ---------
__global__ __launch_bounds__(256, 2) void k_out_mfma(
    const float* __restrict__ agg, const float* __restrict__ x,
    const u16* __restrict__ wf2, const float* __restrict__ ba,
    const float* __restrict__ bo, float* __restrict__ outb)
{
    __shared__ u16 p_lds[2][64][256];       // 64 KB; reused as float Cs[64][256]
    const int tid = threadIdx.x;
    const int w = tid >> 6;
    const int lane = tid & 63;
    const int l31 = lane & 31;
    const int g2 = lane >> 5;
    const int n0 = blockIdx.x * 64;
    const unsigned swz = ((unsigned)(l31 & 7)) << 4;

    f32x16 accM[2][2], accC[2][2];
#pragma unroll
    for (int mt = 0; mt < 2; ++mt)
#pragma unroll
        for (int nt = 0; nt < 2; ++nt) { accM[mt][nt] = (f32x16)0.f; accC[mt][nt] = (f32x16)0.f; }

    f16x8 afA[2][2], afB[2][2];

#define PREFA2(DST, GKS) { \
    const u16* pb_ = wf2 + ((size_t)((GKS) * 4 + w) * 4) * 512 + lane * 8; \
    _Pragma("unroll") for (int mt_ = 0; mt_ < 2; ++mt_) \
    _Pragma("unroll") for (int pl_ = 0; pl_ < 2; ++pl_) \
        DST[mt_][pl_] = *(const f16x8*)(const void*)(pb_ + (mt_ * 2 + pl_) * 512); }

#define OSTAGE(SRC) { \
    _Pragma("unroll") for (int i_ = 0; i_ < 16; ++i_) { \
        const int ln_ = w * 16 + i_; \
        float4 v_ = *(const float4*)((SRC) + (size_t)(n0 + ln_) * DIM + lane * 4); \
        float pv_[4] = {v_.x, v_.y, v_.z, v_.w}; \
        u16x4 v1_, v2_; \
        _Pragma("unroll") for (int j_ = 0; j_ < 4; ++j_) { \
            float f_ = pv_[j_]; \
            _Float16 h1_ = (_Float16)f_; \
            _Float16 h2_ = (_Float16)((f_ - (float)h1_) * 2048.f); \
            v1_[j_] = h_bits(h1_); v2_[j_] = h_bits(h2_); } \
        const unsigned off_ = ((unsigned)(lane * 8)) ^ (((unsigned)(ln_ & 7)) << 4); \
        *(u16x4*)((char*)&p_lds[0][ln_][0] + off_) = v1_; \
        *(u16x4*)((char*)&p_lds[1][ln_][0] + off_) = v2_; } }

#define OKSTEP(GKS) { \
    if ((GKS) + 1 < 32) { \
        if ((GKS) & 1) { PREFA2(afA, (GKS) + 1) } else { PREFA2(afB, (GKS) + 1) } \
    } \
    f16x8 bfr[2][2]; \
    _Pragma("unroll") for (int nt_ = 0; nt_ < 2; ++nt_) { \
        const int en_ = nt_ * 32 + l31; \
        const unsigned off_ = ((unsigned)(((GKS) & 15) * 32 + g2 * 16)) ^ swz; \
        _Pragma("unroll") for (int pl_ = 0; pl_ < 2; ++pl_) \
            bfr[nt_][pl_] = *(const f16x8*)(const void*)((const char*)&p_lds[pl_][en_][0] + off_); \
    } \
    _Pragma("unroll") for (int mt_ = 0; mt_ < 2; ++mt_) \
    _Pragma("unroll") for (int nt_ = 0; nt_ < 2; ++nt_) { \
        f16x8 a1_ = ((GKS) & 1) ? afB[mt_][0] : afA[mt_][0]; \
        f16x8 a2_ = ((GKS) & 1) ? afB[mt_][1] : afA[mt_][1]; \
        accM[mt_][nt_] = __builtin_amdgcn_mfma_f32_32x32x16_f16(a1_, bfr[nt_][0], accM[mt_][nt_], 0, 0, 0); \
        accC[mt_][nt_] = __builtin_amdgcn_mfma_f32_32x32x16_f16(a1_, bfr[nt_][1], accC[mt_][nt_], 0, 0, 0); \
        accC[mt_][nt_] = __builtin_amdgcn_mfma_f32_32x32x16_f16(a2_, bfr[nt_][0], accC[mt_][nt_], 0, 0, 0); } }

    PREFA2(afA, 0)
    OSTAGE(agg)
    __syncthreads();
    OKSTEP(0)  OKSTEP(1)  OKSTEP(2)  OKSTEP(3)
    OKSTEP(4)  OKSTEP(5)  OKSTEP(6)  OKSTEP(7)
    OKSTEP(8)  OKSTEP(9)  OKSTEP(10) OKSTEP(11)
    OKSTEP(12) OKSTEP(13) OKSTEP(14) OKSTEP(15)
    __syncthreads();
    OSTAGE(x)
    __syncthreads();
    OKSTEP(16) OKSTEP(17) OKSTEP(18) OKSTEP(19)
    OKSTEP(20) OKSTEP(21) OKSTEP(22) OKSTEP(23)
    OKSTEP(24) OKSTEP(25) OKSTEP(26) OKSTEP(27)
    OKSTEP(28) OKSTEP(29) OKSTEP(30) OKSTEP(31)
#undef OSTAGE
#undef OKSTEP
#undef PREFA2

    // ---- epilogue: bias add + LDS transpose + coalesced store ----
    __syncthreads();
    float* Cs = (float*)(void*)p_lds;       // logical [64 nodes][256 outs], swizzled
#pragma unroll
    for (int mt = 0; mt < 2; ++mt)
#pragma unroll
        for (int r = 0; r < 16; ++r) {
            int o = 64 * w + 32 * mt + (r & 3) + 8 * (r >> 2) + 4 * g2;
            float bs = ba[o] + bo[o];
#pragma unroll
            for (int nt = 0; nt < 2; ++nt) {
                int col = nt * 32 + l31;
                float hv = accM[mt][nt][r] + accC[mt][nt][r] * 4.8828125e-4f + bs;
                unsigned ob = ((unsigned)(col * 1024 + o * 4)) ^ (((unsigned)(col & 31)) << 4);
                *(float*)((char*)Cs + ob) = hv;
            }
        }
    __syncthreads();
#pragma unroll
    for (int i = 0; i < 16; ++i) {
        int ln = w * 16 + i;
        unsigned rb = ((unsigned)(ln * 1024 + lane * 16)) ^ (((unsigned)(ln & 31)) << 4);
        float4 val = *(const float4*)((const char*)Cs + rb);
        *(float4*)(outb + (size_t)(n0 + ln) * DIM + lane * 4) = val;
    }
}

// ---------------- BN column stats (fp64 partials) ----------------
__global__ void k_colstat(const float* __restrict__ outb, double* __restrict__ psum,
                          double* __restrict__ psq) {
    int g = blockIdx.x, t = threadIdx.x;
    double s = 0.0, q = 0.0;
    const float* p = outb + (size_t)g * 256 * DIM + t;
    for (int r = 0; r < 256; ++r) { double v = (double)p[(size_t)r * DIM]; s += v; q += v * v; }
    psum[g * DIM + t] = s;
    psq[g * DIM + t] = q;
}

__global__ void k_bnparam(const double* __restrict__ psum, const double* __restrict__ psq,
                          const float* __restrict__ gamma, const float* __restrict__ beta,
                          float* __restrict__ scale, float* __restrict__ shift) {
    int t = threadIdx.x;
    double s = 0.0, q = 0.0;
    for (int g = 0; g < 32; ++g) { s += psum[g * DIM + t]; q += psq[g * DIM + t]; }
    double mean = s / (double)NODES;
    double var = q / (double)NODES - mean * mean;
    float sc = (float)((double)gamma[t] / sqrt(var + 1e-5));
    scale[t] = sc;
    shift[t] = (float)((double)beta[t] - mean * (double)sc);
}

// ---------------- affine + SELU + pooling score ----------------
__global__ void k_bnselu(float* __restrict__ outb, const float* __restrict__ scale,
                         const float* __restrict__ shift, const float* __restrict__ yw,
                         const float* __restrict__ yb, float* __restrict__ y) {
    int gw = (blockIdx.x * blockDim.x + threadIdx.x) >> 6;
    int lane = threadIdx.x & 63;
    if (gw >= NODES) return;
    float4 v  = *(const float4*)(outb + (size_t)gw * DIM + lane * 4);
    float4 sc = *(const float4*)(scale + lane * 4);
    float4 sh = *(const float4*)(shift + lane * 4);
    const float SL = 1.0507009873554805f, SA = 1.6732632423543772f;
    float4 o;
    o.x = v.x * sc.x + sh.x;
    o.y = v.y * sc.y + sh.y;
    o.z = v.z * sc.z + sh.z;
    o.w = v.w * sc.w + sh.w;
    o.x = (o.x > 0.f) ? SL * o.x : SL * SA * expm1f(o.x);
    o.y = (o.y > 0.f) ? SL * o.y : SL * SA * expm1f(o.y);
    o.z = (o.z > 0.f) ? SL * o.z : SL * SA * expm1f(o.z);
    o.w = (o.w > 0.f) ? SL * o.w : SL * SA * expm1f(o.w);
    *(float4*)(outb + (size_t)gw * DIM + lane * 4) = o;
    float4 w = *(const float4*)(yw + lane * 4);
    float z = o.x * w.x + o.y * w.y + o.z * w.z + o.w * w.w;
#pragma unroll
    for (int off = 32; off > 0; off >>= 1) z += __shfl_xor(z, off);
    if (lane == 0) y[gw] = 1.f / (1.f + expf(-(z + yb[0])));
}

// ---------------- per-batch bitonic top-k (val desc, idx asc) ----------------
__global__ void k_topk(const float* __restrict__ y, float* __restrict__ svals,
                       int* __restrict__ sidx) {
    __shared__ float v[1024];
    __shared__ int  id[1024];
    int b = blockIdx.x, t = threadIdx.x;   // 512 threads
    v[t] = y[b * 1024 + t];           id[t] = t;
    v[t + 512] = y[b * 1024 + t + 512]; id[t + 512] = t + 512;
    __syncthreads();
    for (int k = 2; k <= 1024; k <<= 1) {
        for (int j = k >> 1; j > 0; j >>= 1) {
            for (int i = t; i < 1024; i += 512) {
                int l = i ^ j;
                if (l > i) {
                    float vi = v[i], vl = v[l];
                    int ii = id[i], il = id[l];
                    bool precede = (vi > vl) || (vi == vl && ii < il);
                    bool dirDesc = ((i & k) == 0);
                    bool sw = dirDesc ? !precede : precede;
                    if (sw) { v[i] = vl; v[l] = vi; id[i] = il; id[l] = ii; }
                }
            }
            __syncthreads();
        }
    }
    if (t < 512) { svals[b * 512 + t] = v[t]; sidx[b * 512 + t] = id[t]; }
}

// ---------------- gather + gate ----------------
__global__ void k_gather(const float* __restrict__ outb, const float* __restrict__ svals,
                         const int* __restrict__ sidx, float* __restrict__ dout) {
    int gw = (blockIdx.x * blockDim.x + threadIdx.x) >> 6;
    int lane = threadIdx.x & 63;
    int b = gw >> 9, r = gw & 511;
    float val = svals[b * 512 + r];
    int idn = sidx[b * 512 + r];
    float4 vv = *(const float4*)(outb + (size_t)(b * 1024 + idn) * DIM + lane * 4);
    vv.x *= val; vv.y *= val; vv.z *= val; vv.w *= val;
    *(float4*)(dout + (size_t)(b * 512 + r) * DIM + lane * 4) = vv;
}

extern "C" void kernel_launch(void* const* d_in, const int* in_sizes, int n_in,
                              void* d_out, int out_size, void* d_ws, size_t ws_size,
                              hipStream_t stream) {
    const float* x     = (const float*)d_in[0];
    const int* edges   = (const int*)d_in[1];
    const float* att_w = (const float*)d_in[2];
    const float* att_b = (const float*)d_in[3];
    const float* amap  = (const float*)d_in[4];
    const float* pwa_w = (const float*)d_in[5];
    const float* pwa_b = (const float*)d_in[6];
    const float* pwo_w = (const float*)d_in[7];
    const float* pwo_b = (const float*)d_in[8];
    const float* gamma = (const float*)d_in[9];
    const float* beta  = (const float*)d_in[10];
    const float* yw    = (const float*)d_in[11];
    const float* yb    = (const float*)d_in[12];
    float* out = (float*)d_out;
    const int* src = edges;
    const int* dst = edges + NEDGE;

    char* ws = (char*)d_ws;
    size_t off = 0;
    auto alloc = [&](size_t b) { void* p = ws + off; off = (off + b + 255) & ~(size_t)255; return p; };
    float* alpha  = (float*)alloc((size_t)NEDGE * 4);      // CSR-position order
    int2*  sdg    = (int2*)alloc((size_t)NEDGE * 8);       // (src,dst) per CSR position
    float* agg    = (float*)alloc((size_t)NODES * DIM * 4);
    float* outb   = (float*)alloc((size_t)NODES * DIM * 4);
    int*   deg    = (int*)alloc(NODES * 4);
    int*   rowptr = (int*)alloc((NODES + 1) * 4);
    int*   cursor = (int*)alloc(NODES * 4);
    double* psum  = (double*)alloc(32 * DIM * 8);
    double* psq   = (double*)alloc(32 * DIM * 8);
    float* scale  = (float*)alloc(DIM * 4);
    float* shift  = (float*)alloc(DIM * 4);
    float* yv     = (float*)alloc(NODES * 4);
    float* svals  = (float*)alloc(8 * 512 * 4);
    int*   sidx   = (int*)alloc(8 * 512 * 4);
    u16*   wf     = (u16*)alloc((size_t)16 * 4 * 4 * 512 * 2);
    u16*   wf2    = (u16*)alloc((size_t)32 * 4 * 4 * 512 * 2);

    k_wfrag<<<32, 256, 0, stream>>>(att_w, wf);
    k_wfrag2<<<64, 256, 0, stream>>>(pwa_w, pwo_w, wf2);
    k_zero<<<NODES / 256, 256, 0, stream>>>(deg);
    k_deg<<<NEDGE / 256, 256, 0, stream>>>(dst, deg);
    k_scan<<<1, 256, 0, stream>>>(deg, rowptr, cursor);
    k_fill<<<NEDGE / 256, 256, 0, stream>>>(src, dst, cursor, sdg);
    k_alpha_v11<<<NEDGE / 64, 256, 0, stream>>>(x, sdg, wf, att_b, amap, alpha);
    k_aggregate<<<NODES / 4, 256, 0, stream>>>(x, alpha, rowptr, sdg, agg);
    k_out_mfma<<<NODES / 64, 256, 0, stream>>>(agg, x, wf2, pwa_b, pwo_b, outb);
    k_colstat<<<32, 256, 0, stream>>>(outb, psum, psq);
    k_bnparam<<<1, 256, 0, stream>>>(psum, psq, gamma, beta, scale, shift);
    k_bnselu<<<NODES / 4, 256, 0, stream>>>(outb, scale, shift, yw, yb, yv);
    k_topk<<<8, 512, 0, stream>>>(yv, svals, sidx);
    k_gather<<<(8 * 512) / 4, 256, 0, stream>>>(outb, svals, sidx, out);
}

// Round 12
// 266.483 us; speedup vs baseline: 1.5638x; 1.0311x over previous
//
#include <hip/hip_runtime.h>
#include <math.h>

#define NODES 8192
#define NEDGE 262144
#define DIM 256

typedef float f32x16 __attribute__((ext_vector_type(16)));
typedef _Float16 f16x8 __attribute__((ext_vector_type(8)));
typedef unsigned short u16;
typedef u16 u16x8 __attribute__((ext_vector_type(8)));
typedef u16 u16x4 __attribute__((ext_vector_type(4)));

__device__ __forceinline__ float fast_tanh(float x) {
    float t = __expf(2.f * x);
    return 1.f - 2.f * __builtin_amdgcn_rcpf(t + 1.f);
}

__device__ __forceinline__ u16 h_bits(_Float16 h) {
    u16 r; __builtin_memcpy(&r, &h, 2); return r;
}

// ---------------- CSR build (dst-indexed) ----------------
__global__ void k_deg(const int* __restrict__ dst, int* __restrict__ deg) {
    int e = blockIdx.x * blockDim.x + threadIdx.x;
    if (e < NEDGE) atomicAdd(&deg[dst[e]], 1);
}

__global__ void k_scan(const int* __restrict__ deg, int* __restrict__ rowptr,
                       int* __restrict__ cursor) {
    __shared__ int part[256];
    int t = threadIdx.x;
    int base = t * 32;
    int local[32];
    int s = 0;
    for (int i = 0; i < 32; ++i) { local[i] = s; s += deg[base + i]; }
    part[t] = s;
    __syncthreads();
    for (int off = 1; off < 256; off <<= 1) {
        int v = (t >= off) ? part[t - off] : 0;
        __syncthreads();
        part[t] += v;
        __syncthreads();
    }
    int excl = (t == 0) ? 0 : part[t - 1];
    for (int i = 0; i < 32; ++i) {
        int v = excl + local[i];
        rowptr[base + i] = v;
        cursor[base + i] = v;
    }
    if (t == 255) rowptr[NODES] = part[255];
}

// store (src,dst) pair at CSR position -> single-level indirection downstream
__global__ void k_fill(const int* __restrict__ src, const int* __restrict__ dst,
                       int* __restrict__ cursor, int2* __restrict__ sdg) {
    int e = blockIdx.x * blockDim.x + threadIdx.x;
    if (e < NEDGE) {
        int pos = atomicAdd(&cursor[dst[e]], 1);
        sdg[pos] = make_int2(src[e], dst[e]);
    }
}

// ---------------- att_w -> fp16 2-plane fragment order ----------------
__global__ void k_wfrag(const float* __restrict__ W, u16* __restrict__ wf) {
    int t = blockIdx.x * blockDim.x + threadIdx.x;
    if (t >= 16 * 4 * 2 * 64) return;
    int lane = t & 63;
    int mt = (t >> 6) & 1;
    int w = (t >> 7) & 3;
    int gks = t >> 9;
    int row = w * 64 + mt * 32 + (lane & 31);
    int k0 = gks * 16 + (lane >> 5) * 8;
    const float* p = W + (size_t)row * DIM + k0;
    u16x8 v1, v2;
#pragma unroll
    for (int j = 0; j < 8; ++j) {
        float f = p[j];
        _Float16 h1 = (_Float16)f;
        _Float16 h2 = (_Float16)((f - (float)h1) * 2048.f);
        v1[j] = h_bits(h1);
        v2[j] = h_bits(h2);
    }
    size_t base = ((size_t)(gks * 4 + w) * 4 + mt * 2) * 512 + lane * 8;
    *(u16x8*)(wf + base)       = v1;
    *(u16x8*)(wf + base + 512) = v2;
}

// ---------------- [pwa_w ; pwo_w] -> fragment order, K=512 (gks 0..31) -----
__global__ void k_wfrag2(const float* __restrict__ Wa, const float* __restrict__ Wo,
                         u16* __restrict__ wf2) {
    int t = blockIdx.x * blockDim.x + threadIdx.x;
    if (t >= 32 * 4 * 2 * 64) return;
    int lane = t & 63;
    int mt = (t >> 6) & 1;
    int w = (t >> 7) & 3;
    int gks = t >> 9;                       // 0..31
    const float* W = (gks < 16) ? Wa : Wo;
    int row = w * 64 + mt * 32 + (lane & 31);
    int k0 = (gks & 15) * 16 + (lane >> 5) * 8;
    const float* p = W + (size_t)row * DIM + k0;
    u16x8 v1, v2;
#pragma unroll
    for (int j = 0; j < 8; ++j) {
        float f = p[j];
        _Float16 h1 = (_Float16)f;
        _Float16 h2 = (_Float16)((f - (float)h1) * 2048.f);
        v1[j] = h_bits(h1);
        v2[j] = h_bits(h2);
    }
    size_t base = ((size_t)(gks * 4 + w) * 4 + mt * 2) * 512 + lane * 8;
    *(u16x8*)(wf2 + base)       = v1;
    *(u16x8*)(wf2 + base + 512) = v2;
}

// ---------------- alpha, v12: v9 base + depth-2 A prefetch (3 buffers) ------
__global__ __launch_bounds__(256, 2) void k_alpha_v12(
    const float* __restrict__ x, const int2* __restrict__ sdg,
    const u16* __restrict__ wf, const float* __restrict__ bias,
    const float* __restrict__ amap, float* __restrict__ alpha_pos)
{
    __shared__ u16 p_lds[2][64][256];   // 64 KB; [plane][edge][k], byte ^ ((edge&7)<<4)
    const int tid = threadIdx.x;
    const int w = tid >> 6;
    const int lane = tid & 63;
    const int l31 = lane & 31;
    const int g2 = lane >> 5;
    const int bid = blockIdx.x;
    const int wg = (bid & 7) * 512 + (bid >> 3);   // XCD swizzle (4096%8==0)
    const int e0 = wg * 64;
    const int ebase = e0 + w * 16;
    const unsigned swz = ((unsigned)(l31 & 7)) << 4;

    f32x16 accM[2][2], accC[2][2];
#pragma unroll
    for (int mt = 0; mt < 2; ++mt)
#pragma unroll
        for (int nt = 0; nt < 2; ++nt) { accM[mt][nt] = (f32x16)0.f; accC[mt][nt] = (f32x16)0.f; }

    f16x8 afA[2][2], afB[2][2], afC[2][2];

#define PREFA(DST, GKS) { \
    const u16* pb_ = wf + ((size_t)((GKS) * 4 + w) * 4) * 512 + lane * 8; \
    _Pragma("unroll") for (int mt_ = 0; mt_ < 2; ++mt_) \
    _Pragma("unroll") for (int pl_ = 0; pl_ < 2; ++pl_) \
        DST[mt_][pl_] = *(const f16x8*)(const void*)(pb_ + (mt_ * 2 + pl_) * 512); }

// KSTEP with explicit use-buffer and prefetch-buffer (depth-2 rotation)
#define KS(GKS, USE, PF) { \
    if ((GKS) + 2 < 16) { PREFA(PF, (GKS) + 2) } \
    f16x8 bfr[2][2]; \
    _Pragma("unroll") for (int nt_ = 0; nt_ < 2; ++nt_) { \
        const int en_ = nt_ * 32 + l31; \
        const unsigned off_ = ((unsigned)((GKS) * 32 + g2 * 16)) ^ swz; \
        _Pragma("unroll") for (int pl_ = 0; pl_ < 2; ++pl_) \
            bfr[nt_][pl_] = *(const f16x8*)(const void*)((const char*)&p_lds[pl_][en_][0] + off_); \
    } \
    _Pragma("unroll") for (int mt_ = 0; mt_ < 2; ++mt_) \
    _Pragma("unroll") for (int nt_ = 0; nt_ < 2; ++nt_) { \
        accM[mt_][nt_] = __builtin_amdgcn_mfma_f32_32x32x16_f16(USE[mt_][0], bfr[nt_][0], accM[mt_][nt_], 0, 0, 0); \
        accC[mt_][nt_] = __builtin_amdgcn_mfma_f32_32x32x16_f16(USE[mt_][0], bfr[nt_][1], accC[mt_][nt_], 0, 0, 0); \
        accC[mt_][nt_] = __builtin_amdgcn_mfma_f32_32x32x16_f16(USE[mt_][1], bfr[nt_][0], accC[mt_][nt_], 0, 0, 0); } }

    // preload A(0), A(1) before the gather burst (in-order vmcnt: A completes first)
    PREFA(afA, 0)
    PREFA(afB, 1)

    // ---- cooperative staging: wave w stages edges [16w, 16w+16), full K ----
#pragma unroll
    for (int i = 0; i < 16; ++i) {
        int2 sd = sdg[ebase + i];
        float4 a = *(const float4*)(x + (size_t)sd.x * DIM + lane * 4);
        float4 b = *(const float4*)(x + (size_t)sd.y * DIM + lane * 4);
        float pv[4] = {a.x * b.x, a.y * b.y, a.z * b.z, a.w * b.w};
        u16x4 v1, v2;
#pragma unroll
        for (int j = 0; j < 4; ++j) {
            float f = pv[j];
            _Float16 h1 = (_Float16)f;
            _Float16 h2 = (_Float16)((f - (float)h1) * 2048.f);
            v1[j] = h_bits(h1);
            v2[j] = h_bits(h2);
        }
        const int le = w * 16 + i;
        const unsigned off = ((unsigned)(lane * 8)) ^ (((unsigned)(le & 7)) << 4);
        *(u16x4*)((char*)&p_lds[0][le][0] + off) = v1;
        *(u16x4*)((char*)&p_lds[1][le][0] + off) = v2;
    }
    __syncthreads();

    // ---- 16-step MFMA burst, A prefetched 2 steps ahead (buf rotation mod 3) ----
    KS(0,  afA, afC) KS(1,  afB, afA) KS(2,  afC, afB)
    KS(3,  afA, afC) KS(4,  afB, afA) KS(5,  afC, afB)
    KS(6,  afA, afC) KS(7,  afB, afA) KS(8,  afC, afB)
    KS(9,  afA, afC) KS(10, afB, afA) KS(11, afC, afB)
    KS(12, afA, afC) KS(13, afB, afA) KS(14, afC, afB)
    KS(15, afA, afC)
#undef KS
#undef PREFA

    // ---- epilogue: alpha = sum_out amap*tanh(h+bias), h = M + C*2^-11 ----
    float part[2] = {0.f, 0.f};
#pragma unroll
    for (int mt = 0; mt < 2; ++mt)
#pragma unroll
        for (int r = 0; r < 16; ++r) {
            int o = 64 * w + 32 * mt + (r & 3) + 8 * (r >> 2) + 4 * g2;
            float bo = bias[o], ao = amap[o];
#pragma unroll
            for (int nt = 0; nt < 2; ++nt) {
                float h = accM[mt][nt][r] + accC[mt][nt][r] * 4.8828125e-4f;
                part[nt] += ao * fast_tanh(h + bo);
            }
        }
    __syncthreads();                       // all LDS reads done; reuse p_lds for reduction
    float* red = (float*)(void*)p_lds;     // [4][64]
#pragma unroll
    for (int nt = 0; nt < 2; ++nt) {
        float p = part[nt];
        p += __shfl_xor(p, 32);
        if (lane < 32) red[w * 64 + nt * 32 + lane] = p;
    }
    __syncthreads();
    if (tid < 64) alpha_pos[e0 + tid] = red[tid] + red[64 + tid] + red[128 + tid] + red[192 + tid];
}

// ---------------- segment softmax + weighted aggregate (unroll-4) ----------
__global__ void k_aggregate(
    const float* __restrict__ x, const float* __restrict__ alpha_pos,
    const int* __restrict__ rowptr, const int2* __restrict__ sdg,
    float* __restrict__ agg)
{
    int gw = (blockIdx.x * blockDim.x + threadIdx.x) >> 6;
    int lane = threadIdx.x & 63;
    if (gw >= NODES) return;
    int start = rowptr[gw], end = rowptr[gw + 1];
    int deg = end - start;
    float m = -INFINITY;
    for (int i = lane; i < deg; i += 64) m = fmaxf(m, alpha_pos[start + i]);
#pragma unroll
    for (int off = 32; off > 0; off >>= 1) m = fmaxf(m, __shfl_xor(m, off));
    float ssum = 0.f;
    for (int i = lane; i < deg; i += 64) ssum += expf(alpha_pos[start + i] - m);
#pragma unroll
    for (int off = 32; off > 0; off >>= 1) ssum += __shfl_xor(ssum, off);
    float a0 = 0.f, a1 = 0.f, a2 = 0.f, a3 = 0.f;
    int i = 0;
    for (; i + 4 <= deg; i += 4) {
        float w0 = expf(alpha_pos[start + i]     - m);
        float w1 = expf(alpha_pos[start + i + 1] - m);
        float w2 = expf(alpha_pos[start + i + 2] - m);
        float w3 = expf(alpha_pos[start + i + 3] - m);
        int r0 = sdg[start + i].x;
        int r1 = sdg[start + i + 1].x;
        int r2 = sdg[start + i + 2].x;
        int r3 = sdg[start + i + 3].x;
        float4 v0 = *(const float4*)(x + (size_t)r0 * DIM + lane * 4);
        float4 v1 = *(const float4*)(x + (size_t)r1 * DIM + lane * 4);
        float4 v2 = *(const float4*)(x + (size_t)r2 * DIM + lane * 4);
        float4 v3 = *(const float4*)(x + (size_t)r3 * DIM + lane * 4);
        a0 += w0 * v0.x + w1 * v1.x + w2 * v2.x + w3 * v3.x;
        a1 += w0 * v0.y + w1 * v1.y + w2 * v2.y + w3 * v3.y;
        a2 += w0 * v0.z + w1 * v1.z + w2 * v2.z + w3 * v3.z;
        a3 += w0 * v0.w + w1 * v1.w + w2 * v2.w + w3 * v3.w;
    }
    for (; i < deg; ++i) {
        float wgt = expf(alpha_pos[start + i] - m);
        int r = sdg[start + i].x;
        const float4 v = *(const float4*)(x + (size_t)r * DIM + lane * 4);
        a0 += wgt * v.x; a1 += wgt * v.y; a2 += wgt * v.z; a3 += wgt * v.w;
    }
    float inv = 1.f / (ssum + 1e-16f);
    float4 r; r.x = a0 * inv; r.y = a1 * inv; r.z = a2 * inv; r.w = a3 * inv;
    *(float4*)(agg + (size_t)gw * DIM + lane * 4) = r;
}

// ---------------- out = [agg|x] @ [Wa;Wo]^T + biases, MFMA 2-split ---------
__global__ __launch_bounds__(256, 2) void k_out_mfma(
    const float* __restrict__ agg, const float* __restrict__ x,
    const u16* __restrict__ wf2, const float* __restrict__ ba,
    const float* __restrict__ bo, float* __restrict__ outb)
{
    __shared__ u16 p_lds[2][64][256];       // 64 KB; reused as float Cs[64][256]
    const int tid = threadIdx.x;
    const int w = tid >> 6;
    const int lane = tid & 63;
    const int l31 = lane & 31;
    const int g2 = lane >> 5;
    const int n0 = blockIdx.x * 64;
    const unsigned swz = ((unsigned)(l31 & 7)) << 4;

    f32x16 accM[2][2], accC[2][2];
#pragma unroll
    for (int mt = 0; mt < 2; ++mt)
#pragma unroll
        for (int nt = 0; nt < 2; ++nt) { accM[mt][nt] = (f32x16)0.f; accC[mt][nt] = (f32x16)0.f; }

    f16x8 afA[2][2], afB[2][2];

#define PREFA2(DST, GKS) { \
    const u16* pb_ = wf2 + ((size_t)((GKS) * 4 + w) * 4) * 512 + lane * 8; \
    _Pragma("unroll") for (int mt_ = 0; mt_ < 2; ++mt_) \
    _Pragma("unroll") for (int pl_ = 0; pl_ < 2; ++pl_) \
        DST[mt_][pl_] = *(const f16x8*)(const void*)(pb_ + (mt_ * 2 + pl_) * 512); }

#define OSTAGE(SRC) { \
    _Pragma("unroll") for (int i_ = 0; i_ < 16; ++i_) { \
        const int ln_ = w * 16 + i_; \
        float4 v_ = *(const float4*)((SRC) + (size_t)(n0 + ln_) * DIM + lane * 4); \
        float pv_[4] = {v_.x, v_.y, v_.z, v_.w}; \
        u16x4 v1_, v2_; \
        _Pragma("unroll") for (int j_ = 0; j_ < 4; ++j_) { \
            float f_ = pv_[j_]; \
            _Float16 h1_ = (_Float16)f_; \
            _Float16 h2_ = (_Float16)((f_ - (float)h1_) * 2048.f); \
            v1_[j_] = h_bits(h1_); v2_[j_] = h_bits(h2_); } \
        const unsigned off_ = ((unsigned)(lane * 8)) ^ (((unsigned)(ln_ & 7)) << 4); \
        *(u16x4*)((char*)&p_lds[0][ln_][0] + off_) = v1_; \
        *(u16x4*)((char*)&p_lds[1][ln_][0] + off_) = v2_; } }

#define OKSTEP(GKS) { \
    if ((GKS) + 1 < 32) { \
        if ((GKS) & 1) { PREFA2(afA, (GKS) + 1) } else { PREFA2(afB, (GKS) + 1) } \
    } \
    f16x8 bfr[2][2]; \
    _Pragma("unroll") for (int nt_ = 0; nt_ < 2; ++nt_) { \
        const int en_ = nt_ * 32 + l31; \
        const unsigned off_ = ((unsigned)(((GKS) & 15) * 32 + g2 * 16)) ^ swz; \
        _Pragma("unroll") for (int pl_ = 0; pl_ < 2; ++pl_) \
            bfr[nt_][pl_] = *(const f16x8*)(const void*)((const char*)&p_lds[pl_][en_][0] + off_); \
    } \
    _Pragma("unroll") for (int mt_ = 0; mt_ < 2; ++mt_) \
    _Pragma("unroll") for (int nt_ = 0; nt_ < 2; ++nt_) { \
        f16x8 a1_ = ((GKS) & 1) ? afB[mt_][0] : afA[mt_][0]; \
        f16x8 a2_ = ((GKS) & 1) ? afB[mt_][1] : afA[mt_][1]; \
        accM[mt_][nt_] = __builtin_amdgcn_mfma_f32_32x32x16_f16(a1_, bfr[nt_][0], accM[mt_][nt_], 0, 0, 0); \
        accC[mt_][nt_] = __builtin_amdgcn_mfma_f32_32x32x16_f16(a1_, bfr[nt_][1], accC[mt_][nt_], 0, 0, 0); \
        accC[mt_][nt_] = __builtin_amdgcn_mfma_f32_32x32x16_f16(a2_, bfr[nt_][0], accC[mt_][nt_], 0, 0, 0); } }

    PREFA2(afA, 0)
    OSTAGE(agg)
    __syncthreads();
    OKSTEP(0)  OKSTEP(1)  OKSTEP(2)  OKSTEP(3)
    OKSTEP(4)  OKSTEP(5)  OKSTEP(6)  OKSTEP(7)
    OKSTEP(8)  OKSTEP(9)  OKSTEP(10) OKSTEP(11)
    OKSTEP(12) OKSTEP(13) OKSTEP(14) OKSTEP(15)
    __syncthreads();
    OSTAGE(x)
    __syncthreads();
    OKSTEP(16) OKSTEP(17) OKSTEP(18) OKSTEP(19)
    OKSTEP(20) OKSTEP(21) OKSTEP(22) OKSTEP(23)
    OKSTEP(24) OKSTEP(25) OKSTEP(26) OKSTEP(27)
    OKSTEP(28) OKSTEP(29) OKSTEP(30) OKSTEP(31)
#undef OSTAGE
#undef OKSTEP
#undef PREFA2

    // ---- epilogue: bias add + LDS transpose + coalesced store ----
    __syncthreads();
    float* Cs = (float*)(void*)p_lds;       // logical [64 nodes][256 outs], swizzled
#pragma unroll
    for (int mt = 0; mt < 2; ++mt)
#pragma unroll
        for (int r = 0; r < 16; ++r) {
            int o = 64 * w + 32 * mt + (r & 3) + 8 * (r >> 2) + 4 * g2;
            float bs = ba[o] + bo[o];
#pragma unroll
            for (int nt = 0; nt < 2; ++nt) {
                int col = nt * 32 + l31;
                float hv = accM[mt][nt][r] + accC[mt][nt][r] * 4.8828125e-4f + bs;
                unsigned ob = ((unsigned)(col * 1024 + o * 4)) ^ (((unsigned)(col & 31)) << 4);
                *(float*)((char*)Cs + ob) = hv;
            }
        }
    __syncthreads();
#pragma unroll
    for (int i = 0; i < 16; ++i) {
        int ln = w * 16 + i;
        unsigned rb = ((unsigned)(ln * 1024 + lane * 16)) ^ (((unsigned)(ln & 31)) << 4);
        float4 val = *(const float4*)((const char*)Cs + rb);
        *(float4*)(outb + (size_t)(n0 + ln) * DIM + lane * 4) = val;
    }
}

// ---------------- BN column stats (fp64 partials) ----------------
__global__ void k_colstat(const float* __restrict__ outb, double* __restrict__ psum,
                          double* __restrict__ psq) {
    int g = blockIdx.x, t = threadIdx.x;
    double s = 0.0, q = 0.0;
    const float* p = outb + (size_t)g * 256 * DIM + t;
    for (int r = 0; r < 256; ++r) { double v = (double)p[(size_t)r * DIM]; s += v; q += v * v; }
    psum[g * DIM + t] = s;
    psq[g * DIM + t] = q;
}

__global__ void k_bnparam(const double* __restrict__ psum, const double* __restrict__ psq,
                          const float* __restrict__ gamma, const float* __restrict__ beta,
                          float* __restrict__ scale, float* __restrict__ shift) {
    int t = threadIdx.x;
    double s = 0.0, q = 0.0;
    for (int g = 0; g < 32; ++g) { s += psum[g * DIM + t]; q += psq[g * DIM + t]; }
    double mean = s / (double)NODES;
    double var = q / (double)NODES - mean * mean;
    float sc = (float)((double)gamma[t] / sqrt(var + 1e-5));
    scale[t] = sc;
    shift[t] = (float)((double)beta[t] - mean * (double)sc);
}

// ---------------- affine + SELU + pooling score ----------------
__global__ void k_bnselu(float* __restrict__ outb, const float* __restrict__ scale,
                         const float* __restrict__ shift, const float* __restrict__ yw,
                         const float* __restrict__ yb, float* __restrict__ y) {
    int gw = (blockIdx.x * blockDim.x + threadIdx.x) >> 6;
    int lane = threadIdx.x & 63;
    if (gw >= NODES) return;
    float4 v  = *(const float4*)(outb + (size_t)gw * DIM + lane * 4);
    float4 sc = *(const float4*)(scale + lane * 4);
    float4 sh = *(const float4*)(shift + lane * 4);
    const float SL = 1.0507009873554805f, SA = 1.6732632423543772f;
    float4 o;
    o.x = v.x * sc.x + sh.x;
    o.y = v.y * sc.y + sh.y;
    o.z = v.z * sc.z + sh.z;
    o.w = v.w * sc.w + sh.w;
    o.x = (o.x > 0.f) ? SL * o.x : SL * SA * expm1f(o.x);
    o.y = (o.y > 0.f) ? SL * o.y : SL * SA * expm1f(o.y);
    o.z = (o.z > 0.f) ? SL * o.z : SL * SA * expm1f(o.z);
    o.w = (o.w > 0.f) ? SL * o.w : SL * SA * expm1f(o.w);
    *(float4*)(outb + (size_t)gw * DIM + lane * 4) = o;
    float4 w = *(const float4*)(yw + lane * 4);
    float z = o.x * w.x + o.y * w.y + o.z * w.z + o.w * w.w;
#pragma unroll
    for (int off = 32; off > 0; off >>= 1) z += __shfl_xor(z, off);
    if (lane == 0) y[gw] = 1.f / (1.f + expf(-(z + yb[0])));
}

// ---------------- per-batch bitonic top-k (val desc, idx asc) ----------------
__global__ void k_topk(const float* __restrict__ y, float* __restrict__ svals,
                       int* __restrict__ sidx) {
    __shared__ float v[1024];
    __shared__ int  id[1024];
    int b = blockIdx.x, t = threadIdx.x;   // 512 threads
    v[t] = y[b * 1024 + t];           id[t] = t;
    v[t + 512] = y[b * 1024 + t + 512]; id[t + 512] = t + 512;
    __syncthreads();
    for (int k = 2; k <= 1024; k <<= 1) {
        for (int j = k >> 1; j > 0; j >>= 1) {
            for (int i = t; i < 1024; i += 512) {
                int l = i ^ j;
                if (l > i) {
                    float vi = v[i], vl = v[l];
                    int ii = id[i], il = id[l];
                    bool precede = (vi > vl) || (vi == vl && ii < il);
                    bool dirDesc = ((i & k) == 0);
                    bool sw = dirDesc ? !precede : precede;
                    if (sw) { v[i] = vl; v[l] = vi; id[i] = il; id[l] = ii; }
                }
            }
            __syncthreads();
        }
    }
    if (t < 512) { svals[b * 512 + t] = v[t]; sidx[b * 512 + t] = id[t]; }
}

// ---------------- gather + gate ----------------
__global__ void k_gather(const float* __restrict__ outb, const float* __restrict__ svals,
                         const int* __restrict__ sidx, float* __restrict__ dout) {
    int gw = (blockIdx.x * blockDim.x + threadIdx.x) >> 6;
    int lane = threadIdx.x & 63;
    int b = gw >> 9, r = gw & 511;
    float val = svals[b * 512 + r];
    int idn = sidx[b * 512 + r];
    float4 vv = *(const float4*)(outb + (size_t)(b * 1024 + idn) * DIM + lane * 4);
    vv.x *= val; vv.y *= val; vv.z *= val; vv.w *= val;
    *(float4*)(dout + (size_t)(b * 512 + r) * DIM + lane * 4) = vv;
}

extern "C" void kernel_launch(void* const* d_in, const int* in_sizes, int n_in,
                              void* d_out, int out_size, void* d_ws, size_t ws_size,
                              hipStream_t stream) {
    const float* x     = (const float*)d_in[0];
    const int* edges   = (const int*)d_in[1];
    const float* att_w = (const float*)d_in[2];
    const float* att_b = (const float*)d_in[3];
    const float* amap  = (const float*)d_in[4];
    const float* pwa_w = (const float*)d_in[5];
    const float* pwa_b = (const float*)d_in[6];
    const float* pwo_w = (const float*)d_in[7];
    const float* pwo_b = (const float*)d_in[8];
    const float* gamma = (const float*)d_in[9];
    const float* beta  = (const float*)d_in[10];
    const float* yw    = (const float*)d_in[11];
    const float* yb    = (const float*)d_in[12];
    float* out = (float*)d_out;
    const int* src = edges;
    const int* dst = edges + NEDGE;

    char* ws = (char*)d_ws;
    size_t off = 0;
    auto alloc = [&](size_t b) { void* p = ws + off; off = (off + b + 255) & ~(size_t)255; return p; };
    float* alpha  = (float*)alloc((size_t)NEDGE * 4);      // CSR-position order
    int2*  sdg    = (int2*)alloc((size_t)NEDGE * 8);       // (src,dst) per CSR position
    float* agg    = (float*)alloc((size_t)NODES * DIM * 4);
    float* outb   = (float*)alloc((size_t)NODES * DIM * 4);
    int*   deg    = (int*)alloc(NODES * 4);
    int*   rowptr = (int*)alloc((NODES + 1) * 4);
    int*   cursor = (int*)alloc(NODES * 4);
    double* psum  = (double*)alloc(32 * DIM * 8);
    double* psq   = (double*)alloc(32 * DIM * 8);
    float* scale  = (float*)alloc(DIM * 4);
    float* shift  = (float*)alloc(DIM * 4);
    float* yv     = (float*)alloc(NODES * 4);
    float* svals  = (float*)alloc(8 * 512 * 4);
    int*   sidx   = (int*)alloc(8 * 512 * 4);
    u16*   wf     = (u16*)alloc((size_t)16 * 4 * 4 * 512 * 2);
    u16*   wf2    = (u16*)alloc((size_t)32 * 4 * 4 * 512 * 2);

    hipMemsetAsync(deg, 0, NODES * 4, stream);
    k_wfrag<<<32, 256, 0, stream>>>(att_w, wf);
    k_wfrag2<<<64, 256, 0, stream>>>(pwa_w, pwo_w, wf2);
    k_deg<<<NEDGE / 256, 256, 0, stream>>>(dst, deg);
    k_scan<<<1, 256, 0, stream>>>(deg, rowptr, cursor);
    k_fill<<<NEDGE / 256, 256, 0, stream>>>(src, dst, cursor, sdg);
    k_alpha_v12<<<NEDGE / 64, 256, 0, stream>>>(x, sdg, wf, att_b, amap, alpha);
    k_aggregate<<<NODES / 4, 256, 0, stream>>>(x, alpha, rowptr, sdg, agg);
    k_out_mfma<<<NODES / 64, 256, 0, stream>>>(agg, x, wf2, pwa_b, pwo_b, outb);
    k_colstat<<<32, 256, 0, stream>>>(outb, psum, psq);
    k_bnparam<<<1, 256, 0, stream>>>(psum, psq, gamma, beta, scale, shift);
    k_bnselu<<<NODES / 4, 256, 0, stream>>>(outb, scale, shift, yw, yb, yv);
    k_topk<<<8, 512, 0, stream>>>(yv, svals, sidx);
    k_gather<<<(8 * 512) / 4, 256, 0, stream>>>(outb, svals, sidx, out);
}